// Round 5
// baseline (896.203 us; speedup 1.0000x reference)
//
#include <hip/hip_runtime.h>
#include <cmath>

#define N_   8
#define H_   56
#define W_   56
#define C_   256
#define HW_  3136
#define NHW_ 25088
#define G_   8
#define GC_  32
#define P_   9
#define HID_ 1024
#define XP_H 58
#define XP_W 58

typedef __attribute__((ext_vector_type(8))) short bf16x8;
typedef __attribute__((ext_vector_type(4))) float f32x4;

__device__ __forceinline__ unsigned short f2bf(float f) {
    unsigned u = __float_as_uint(f);
    u += 0x7FFF + ((u >> 16) & 1);   // round-to-nearest-even
    return (unsigned short)(u >> 16);
}

__device__ __forceinline__ float gelu_exact(float v) {
    return 0.5f * v * (1.f + erff(v * 0.70710678118654752f));
}

// ---------------- block-wide sum of (a,b) over 256 threads ----------------
__device__ __forceinline__ float2 block_sum2(float a, float b, float* sm) {
    int lane = threadIdx.x & 63;
    int wid  = threadIdx.x >> 6;
#pragma unroll
    for (int off = 32; off > 0; off >>= 1) {
        a += __shfl_down(a, off, 64);
        b += __shfl_down(b, off, 64);
    }
    if (lane == 0) { sm[wid] = a; sm[wid + 4] = b; }
    __syncthreads();
    float ra = sm[0] + sm[1] + sm[2] + sm[3];
    float rb = sm[4] + sm[5] + sm[6] + sm[7];
    __syncthreads();
    return make_float2(ra, rb);
}

// ---------------- x (NCHW fp32) -> xpad (N,58,58,256 bf16), border pre-zeroed ----------------
__global__ __launch_bounds__(256) void k_prep_xpad(const float* __restrict__ x, unsigned short* __restrict__ xpad) {
    int nh = blockIdx.x;                   // N_*H_ = 448
    int n = nh / H_, h = nh - n * H_;
    int c = threadIdx.x;
    const float* xr = x + ((size_t)(n * C_ + c)) * HW_ + h * W_;
    unsigned short* orow = xpad + ((size_t)((n * XP_H + h + 1) * XP_W + 1)) * C_ + c;
    for (int w = 0; w < W_; ++w) orow[(size_t)w * C_] = f2bf(xr[w]);
}

// ---------------- conv1 weights [co][ci][3][3] -> wTT [kk][co][ci] bf16 ----------------
__global__ __launch_bounds__(256) void k_prep_wTT(const float* __restrict__ w, unsigned short* __restrict__ wTT) {
    int i  = blockIdx.x * 256 + threadIdx.x;   // 9*256*256
    int ci = i & 255;
    int r  = i >> 8;
    int co = r & 255;
    int kk = r >> 8;
    wTT[i] = f2bf(w[(co * 256 + ci) * 9 + kk]);
}

// ---------------- square 256x256 weight -> W^T bf16 [n][k] ----------------
__global__ __launch_bounds__(256) void k_prep_sqT(const float* __restrict__ src, unsigned short* __restrict__ dst) {
    int n = blockIdx.x, k = threadIdx.x;
    dst[n * C_ + k] = f2bf(src[k * C_ + n]);
}

// ---------------- fc1 [256][1024] -> [1024][256] bf16 ----------------
__global__ __launch_bounds__(256) void k_prep_fc1T(const float* __restrict__ src, unsigned short* __restrict__ dst) {
    int n = blockIdx.x, k = threadIdx.x;
    dst[(size_t)n * C_ + k] = f2bf(src[(size_t)k * HID_ + n]);
}

// ---------------- fc2 [1024][256] -> [256][1024] bf16 ----------------
__global__ __launch_bounds__(256) void k_prep_fc2T(const float* __restrict__ src, unsigned short* __restrict__ dst) {
    int n = blockIdx.x, k0 = threadIdx.x;
#pragma unroll
    for (int q = 0; q < 4; ++q) {
        int k = q * 256 + k0;
        dst[(size_t)n * HID_ + k] = f2bf(src[(size_t)k * C_ + n]);
    }
}

// ---------------- offw[256][144] + mskw[256][72] -> omT [256][256] bf16 (+ omb) ----------------
__global__ __launch_bounds__(256) void k_prep_om(const float* __restrict__ offw, const float* __restrict__ offb,
                                                 const float* __restrict__ mskw, const float* __restrict__ mskb,
                                                 unsigned short* __restrict__ omT, float* __restrict__ omb) {
    int n = blockIdx.x, k = threadIdx.x;
    float v = 0.f;
    if (n < 144)      v = offw[k * 144 + n];
    else if (n < 216) v = mskw[k * 72 + (n - 144)];
    omT[n * C_ + k] = f2bf(v);
    if (k == 0) omb[n] = (n < 144) ? offb[n] : (n < 216 ? mskb[n - 144] : 0.f);
}

// ---------------- conv1 via MFMA implicit GEMM + BN1 + ReLU -> t (f32) + t_bf ----------------
__global__ __launch_bounds__(256) void k_conv1_mfma(const unsigned short* __restrict__ xpad,
                                                    const unsigned short* __restrict__ wTT,
                                                    const float* __restrict__ g, const float* __restrict__ b,
                                                    const float* __restrict__ m, const float* __restrict__ v,
                                                    float* __restrict__ t, unsigned short* __restrict__ t_bf) {
    int wave = threadIdx.x >> 6;
    int lane = threadIdx.x & 63;
    int r    = lane & 15;
    int kq   = lane >> 4;
    int co0  = wave * 64;
    int p0   = blockIdx.x * 32;

    size_t abase[2];
#pragma unroll
    for (int mi = 0; mi < 2; ++mi) {
        int pix = p0 + mi * 16 + r;
        int n = pix / HW_, hw = pix - n * HW_;
        int h = hw / W_,  w = hw - h * W_;
        abase[mi] = ((size_t)((n * XP_H + h) * XP_W + w)) * C_ + kq * 8;
    }

    f32x4 acc[2][4] = {};
#pragma unroll 1
    for (int tap = 0; tap < 9; ++tap) {
        int kh = tap / 3, kw = tap - kh * 3;
        size_t aoff = (size_t)(kh * XP_W + kw) * C_;
        const unsigned short* bp = wTT + ((size_t)(tap * C_) + co0 + r) * C_ + kq * 8;
        const unsigned short* a0p = xpad + abase[0] + aoff;
        const unsigned short* a1p = xpad + abase[1] + aoff;
#pragma unroll
        for (int ks = 0; ks < 8; ++ks) {
            bf16x8 a0 = *(const bf16x8*)(a0p + ks * 32);
            bf16x8 a1 = *(const bf16x8*)(a1p + ks * 32);
            bf16x8 b0 = *(const bf16x8*)(bp + 0 * 16 * C_ + ks * 32);
            bf16x8 b1 = *(const bf16x8*)(bp + 1 * 16 * C_ + ks * 32);
            bf16x8 b2 = *(const bf16x8*)(bp + 2 * 16 * C_ + ks * 32);
            bf16x8 b3 = *(const bf16x8*)(bp + 3 * 16 * C_ + ks * 32);
            acc[0][0] = __builtin_amdgcn_mfma_f32_16x16x32_bf16(a0, b0, acc[0][0], 0, 0, 0);
            acc[0][1] = __builtin_amdgcn_mfma_f32_16x16x32_bf16(a0, b1, acc[0][1], 0, 0, 0);
            acc[0][2] = __builtin_amdgcn_mfma_f32_16x16x32_bf16(a0, b2, acc[0][2], 0, 0, 0);
            acc[0][3] = __builtin_amdgcn_mfma_f32_16x16x32_bf16(a0, b3, acc[0][3], 0, 0, 0);
            acc[1][0] = __builtin_amdgcn_mfma_f32_16x16x32_bf16(a1, b0, acc[1][0], 0, 0, 0);
            acc[1][1] = __builtin_amdgcn_mfma_f32_16x16x32_bf16(a1, b1, acc[1][1], 0, 0, 0);
            acc[1][2] = __builtin_amdgcn_mfma_f32_16x16x32_bf16(a1, b2, acc[1][2], 0, 0, 0);
            acc[1][3] = __builtin_amdgcn_mfma_f32_16x16x32_bf16(a1, b3, acc[1][3], 0, 0, 0);
        }
    }

#pragma unroll
    for (int ni = 0; ni < 4; ++ni) {
        int co = co0 + ni * 16 + r;
        float sc = g[co] * rsqrtf(v[co] + 1e-5f);
        float sh = b[co] - m[co] * sc;
#pragma unroll
        for (int mi = 0; mi < 2; ++mi) {
#pragma unroll
            for (int reg = 0; reg < 4; ++reg) {
                int pix = p0 + mi * 16 + kq * 4 + reg;
                float val = fmaxf(acc[mi][ni][reg] * sc + sh, 0.f);
                size_t idx = (size_t)pix * C_ + co;
                t[idx] = val;
                t_bf[idx] = f2bf(val);
            }
        }
    }
}

// ---------------- input proj via MFMA: xproj = t_bf @ inpwT^T + b (f32 out) ----------------
__global__ __launch_bounds__(256) void k_inproj_mfma(const unsigned short* __restrict__ t_bf,
                                                     const unsigned short* __restrict__ inpwT,
                                                     const float* __restrict__ bias,
                                                     float* __restrict__ xproj) {
    int wave = threadIdx.x >> 6, lane = threadIdx.x & 63;
    int r = lane & 15, kq = lane >> 4;
    int p0 = blockIdx.x * 32, co0 = wave * 64;
    f32x4 acc[2][4] = {};
#pragma unroll 1
    for (int ks = 0; ks < 8; ++ks) {
        bf16x8 a0 = *(const bf16x8*)(t_bf + (size_t)(p0 + r) * C_ + ks * 32 + kq * 8);
        bf16x8 a1 = *(const bf16x8*)(t_bf + (size_t)(p0 + 16 + r) * C_ + ks * 32 + kq * 8);
        const unsigned short* bp = inpwT + (size_t)(co0 + r) * C_ + ks * 32 + kq * 8;
#pragma unroll
        for (int ni = 0; ni < 4; ++ni) {
            bf16x8 b = *(const bf16x8*)(bp + (size_t)ni * 16 * C_);
            acc[0][ni] = __builtin_amdgcn_mfma_f32_16x16x32_bf16(a0, b, acc[0][ni], 0, 0, 0);
            acc[1][ni] = __builtin_amdgcn_mfma_f32_16x16x32_bf16(a1, b, acc[1][ni], 0, 0, 0);
        }
    }
#pragma unroll
    for (int ni = 0; ni < 4; ++ni) {
        int col = co0 + ni * 16 + r;
        float bb = bias[col];
#pragma unroll
        for (int mi = 0; mi < 2; ++mi)
#pragma unroll
            for (int reg = 0; reg < 4; ++reg) {
                int pix = p0 + mi * 16 + kq * 4 + reg;
                xproj[(size_t)pix * C_ + col] = acc[mi][ni][reg] + bb;
            }
    }
}

// ---------------- depthwise 3x3 + LN(1e-6) + exact GELU -> x1_bf ----------------
__global__ __launch_bounds__(256) void k_dw(const float* __restrict__ t, const float* __restrict__ dww,
                                            const float* __restrict__ dwb, const float* __restrict__ lg,
                                            const float* __restrict__ lb, unsigned short* __restrict__ x1_bf) {
    __shared__ float sm[8];
    int pix = blockIdx.x;
    int n = pix / HW_, hw = pix - n * HW_;
    int h = hw / W_,  w = hw - h * W_;
    int c = threadIdx.x;
    float acc = dwb[c];
#pragma unroll
    for (int kh = 0; kh < 3; ++kh) {
        int y = h + kh - 1;
        if ((unsigned)y >= H_) continue;
#pragma unroll
        for (int kw = 0; kw < 3; ++kw) {
            int xx = w + kw - 1;
            if ((unsigned)xx >= W_) continue;
            acc = fmaf(t[(size_t)(n * HW_ + y * W_ + xx) * C_ + c], dww[(kh * 3 + kw) * C_ + c], acc);
        }
    }
    float2 r  = block_sum2(acc, acc * acc, sm);
    float mu  = r.x * (1.f / C_);
    float var = fmaxf(r.y * (1.f / C_) - mu * mu, 0.f);
    float rs  = rsqrtf(var + 1e-6f);
    float val = (acc - mu) * rs * lg[c] + lb[c];
    x1_bf[(size_t)pix * C_ + c] = f2bf(gelu_exact(val));
}

// ---------------- offset+mask via MFMA (N=256: 144 off | 72 msk | 40 pad) + softmax ----------------
__global__ __launch_bounds__(256) void k_offmask_mfma(const unsigned short* __restrict__ x1_bf,
                                                      const unsigned short* __restrict__ omT,
                                                      const float* __restrict__ omb,
                                                      float* __restrict__ offo, float* __restrict__ msko) {
    __shared__ float som[32][225];
    int wave = threadIdx.x >> 6, lane = threadIdx.x & 63;
    int r = lane & 15, kq = lane >> 4;
    int p0 = blockIdx.x * 32, co0 = wave * 64;
    f32x4 acc[2][4] = {};
#pragma unroll 1
    for (int ks = 0; ks < 8; ++ks) {
        bf16x8 a0 = *(const bf16x8*)(x1_bf + (size_t)(p0 + r) * C_ + ks * 32 + kq * 8);
        bf16x8 a1 = *(const bf16x8*)(x1_bf + (size_t)(p0 + 16 + r) * C_ + ks * 32 + kq * 8);
        const unsigned short* bp = omT + (size_t)(co0 + r) * C_ + ks * 32 + kq * 8;
#pragma unroll
        for (int ni = 0; ni < 4; ++ni) {
            bf16x8 b = *(const bf16x8*)(bp + (size_t)ni * 16 * C_);
            acc[0][ni] = __builtin_amdgcn_mfma_f32_16x16x32_bf16(a0, b, acc[0][ni], 0, 0, 0);
            acc[1][ni] = __builtin_amdgcn_mfma_f32_16x16x32_bf16(a1, b, acc[1][ni], 0, 0, 0);
        }
    }
#pragma unroll
    for (int ni = 0; ni < 4; ++ni) {
        int col = co0 + ni * 16 + r;
        if (col < 216) {
            float bb = omb[col];
#pragma unroll
            for (int mi = 0; mi < 2; ++mi)
#pragma unroll
                for (int reg = 0; reg < 4; ++reg)
                    som[mi * 16 + kq * 4 + reg][col] = acc[mi][ni][reg] + bb;
        }
    }
    __syncthreads();
    int tid = threadIdx.x;
#pragma unroll
    for (int i = 0; i < 18; ++i) {
        int j = i * 256 + tid;          // 32*144 = 4608
        int px = j / 144, col = j - px * 144;
        offo[(size_t)(p0 + px) * 144 + col] = som[px][col];
    }
    int px = tid >> 3, g = tid & 7;
    float mx = -1e30f;
#pragma unroll
    for (int p = 0; p < 9; ++p) mx = fmaxf(mx, som[px][144 + g * 9 + p]);
    float e[9], s = 0.f;
#pragma unroll
    for (int p = 0; p < 9; ++p) { e[p] = expf(som[px][144 + g * 9 + p] - mx); s += e[p]; }
    float inv = 1.f / s;
#pragma unroll
    for (int p = 0; p < 9; ++p) msko[(size_t)(p0 + px) * 72 + g * 9 + p] = e[p] * inv;
}

// ---------------- DCNv3 deformable sampling core -> core_bf ----------------
__global__ __launch_bounds__(256) void k_core(const float* __restrict__ xp,
                                              const float* __restrict__ offo, const float* __restrict__ msko,
                                              unsigned short* __restrict__ core_bf) {
    int pix = blockIdx.x;
    int n = pix / HW_, hw = pix - n * HW_;
    int h = hw / W_,  w = hw - h * W_;
    int g  = threadIdx.x >> 5;
    int cc = threadIdx.x & 31;
    const float* op = offo + (size_t)pix * 144 + g * 18;
    const float* mp = msko + (size_t)pix * 72 + g * 9;
    const float* xg = xp + (size_t)n * HW_ * C_ + g * GC_ + cc;
    float acc = 0.f;
#pragma unroll
    for (int p = 0; p < 9; ++p) {
        float gx = (float)(w + (p / 3)) + op[p * 2];
        float gy = (float)(h + (p % 3)) + op[p * 2 + 1];
        float fx = floorf(gx), fy = floorf(gy);
        float wx = gx - fx,   wy = gy - fy;
        int ix = (int)fx - 1, iy = (int)fy - 1;
        float v00 = 0.f, v10 = 0.f, v01 = 0.f, v11 = 0.f;
        bool x0ok = (unsigned)ix < W_, x1ok = (unsigned)(ix + 1) < W_;
        bool y0ok = (unsigned)iy < H_, y1ok = (unsigned)(iy + 1) < H_;
        if (y0ok) {
            const float* rr = xg + (size_t)(iy * W_) * C_;
            if (x0ok) v00 = rr[(size_t)ix * C_];
            if (x1ok) v10 = rr[(size_t)(ix + 1) * C_];
        }
        if (y1ok) {
            const float* rr = xg + (size_t)((iy + 1) * W_) * C_;
            if (x0ok) v01 = rr[(size_t)ix * C_];
            if (x1ok) v11 = rr[(size_t)(ix + 1) * C_];
        }
        float sval = (v00 * (1.f - wx) + v10 * wx) * (1.f - wy)
                   + (v01 * (1.f - wx) + v11 * wx) * wy;
        acc = fmaf(mp[p], sval, acc);
    }
    core_bf[(size_t)pix * C_ + threadIdx.x] = f2bf(acc);
}

// ---------------- output proj MFMA + LN(1e-5) + gamma1 residual -> t, t_bf ----------------
__global__ __launch_bounds__(256) void k_outproj_mfma(const unsigned short* __restrict__ core_bf,
                                                      const unsigned short* __restrict__ outpwT,
                                                      const float* __restrict__ bo,
                                                      const float* __restrict__ g1, const float* __restrict__ lg,
                                                      const float* __restrict__ lb,
                                                      float* __restrict__ t, unsigned short* __restrict__ t_bf) {
    __shared__ float sd[32][260];
    int wave = threadIdx.x >> 6, lane = threadIdx.x & 63;
    int r = lane & 15, kq = lane >> 4;
    int p0 = blockIdx.x * 32, co0 = wave * 64;
    f32x4 acc[2][4] = {};
#pragma unroll 1
    for (int ks = 0; ks < 8; ++ks) {
        bf16x8 a0 = *(const bf16x8*)(core_bf + (size_t)(p0 + r) * C_ + ks * 32 + kq * 8);
        bf16x8 a1 = *(const bf16x8*)(core_bf + (size_t)(p0 + 16 + r) * C_ + ks * 32 + kq * 8);
        const unsigned short* bp = outpwT + (size_t)(co0 + r) * C_ + ks * 32 + kq * 8;
#pragma unroll
        for (int ni = 0; ni < 4; ++ni) {
            bf16x8 b = *(const bf16x8*)(bp + (size_t)ni * 16 * C_);
            acc[0][ni] = __builtin_amdgcn_mfma_f32_16x16x32_bf16(a0, b, acc[0][ni], 0, 0, 0);
            acc[1][ni] = __builtin_amdgcn_mfma_f32_16x16x32_bf16(a1, b, acc[1][ni], 0, 0, 0);
        }
    }
#pragma unroll
    for (int ni = 0; ni < 4; ++ni) {
        int col = co0 + ni * 16 + r;
        float bb = bo[col];
#pragma unroll
        for (int mi = 0; mi < 2; ++mi)
#pragma unroll
            for (int reg = 0; reg < 4; ++reg)
                sd[mi * 16 + kq * 4 + reg][col] = acc[mi][ni][reg] + bb;
    }
    __syncthreads();
    int px = threadIdx.x >> 3, sub = threadIdx.x & 7;
    float s1 = 0.f, s2 = 0.f;
#pragma unroll
    for (int i = 0; i < 8; ++i) {
        float4 vv = *(const float4*)&sd[px][sub * 32 + i * 4];
        s1 += vv.x + vv.y + vv.z + vv.w;
        s2 += vv.x * vv.x + vv.y * vv.y + vv.z * vv.z + vv.w * vv.w;
    }
#pragma unroll
    for (int off = 1; off < 8; off <<= 1) { s1 += __shfl_xor(s1, off, 64); s2 += __shfl_xor(s2, off, 64); }
    float mu  = s1 * (1.f / C_);
    float var = fmaxf(s2 * (1.f / C_) - mu * mu, 0.f);
    float rs  = rsqrtf(var + 1e-5f);
#pragma unroll
    for (int i = 0; i < 32; ++i) {
        int col = sub * 32 + i;
        size_t idx = (size_t)(p0 + px) * C_ + col;
        float tn = t[idx] + g1[col] * ((sd[px][col] - mu) * rs * lg[col] + lb[col]);
        t[idx] = tn;
        t_bf[idx] = f2bf(tn);
    }
}

// ---------------- fc1 GEMM (M=NHW,N=1024,K=256) + GELU -> h_bf ----------------
// 128x256 tile, 4 waves (2x2), BK=64; LDS in fragment-major chunk order (conflict-free b128).
__global__ __launch_bounds__(256) void k_fc1_mfma(const unsigned short* __restrict__ t_bf,
                                                  const unsigned short* __restrict__ fc1wT,
                                                  const float* __restrict__ fc1b,
                                                  unsigned short* __restrict__ h_bf) {
    __shared__ bf16x8 sA[1024];   // chunk = ((mi*2+ksub)*64) + kq*16 + r  (mi<8)
    __shared__ bf16x8 sB[2048];   // chunk = ((nig*2+ksub)*64) + kq*16 + r (nig<16)
    int tid = threadIdx.x;
    int wave = tid >> 6, lane = tid & 63;
    int r = lane & 15, kq = lane >> 4;
    int mt = blockIdx.x >> 2, nt = blockIdx.x & 3;
    int m0 = mt * 128, n0 = nt * 256;
    int wm = wave & 1, wn = wave >> 1;

    f32x4 acc[4][8] = {};
#pragma unroll 1
    for (int kt = 0; kt < 4; ++kt) {
        int k0 = kt * 64;
        bf16x8 stA[4], stB[8];
#pragma unroll
        for (int j = 0; j < 4; ++j) {
            int c = j * 256 + tid;
            int q = c >> 6, ln = c & 63;
            int arow = (q >> 1) * 16 + (ln & 15);
            int cc   = (q & 1) * 4 + (ln >> 4);
            stA[j] = *(const bf16x8*)(t_bf + (size_t)(m0 + arow) * C_ + k0 + cc * 8);
        }
#pragma unroll
        for (int j = 0; j < 8; ++j) {
            int c = j * 256 + tid;
            int q = c >> 6, ln = c & 63;
            int brow = (q >> 1) * 16 + (ln & 15);
            int cc   = (q & 1) * 4 + (ln >> 4);
            stB[j] = *(const bf16x8*)(fc1wT + (size_t)(n0 + brow) * C_ + k0 + cc * 8);
        }
        if (kt) __syncthreads();           // prior tile reads done
#pragma unroll
        for (int j = 0; j < 4; ++j) sA[j * 256 + tid] = stA[j];
#pragma unroll
        for (int j = 0; j < 8; ++j) sB[j * 256 + tid] = stB[j];
        __syncthreads();
#pragma unroll
        for (int ks = 0; ks < 2; ++ks) {
            bf16x8 af[4], bfr[8];
#pragma unroll
            for (int mi = 0; mi < 4; ++mi) af[mi] = sA[((wm * 4 + mi) * 2 + ks) * 64 + lane];
#pragma unroll
            for (int ni = 0; ni < 8; ++ni) bfr[ni] = sB[((wn * 8 + ni) * 2 + ks) * 64 + lane];
#pragma unroll
            for (int mi = 0; mi < 4; ++mi)
#pragma unroll
                for (int ni = 0; ni < 8; ++ni)
                    acc[mi][ni] = __builtin_amdgcn_mfma_f32_16x16x32_bf16(af[mi], bfr[ni], acc[mi][ni], 0, 0, 0);
        }
    }
#pragma unroll
    for (int ni = 0; ni < 8; ++ni) {
        int col = n0 + (wn * 8 + ni) * 16 + r;
        float bb = fc1b[col];
#pragma unroll
        for (int mi = 0; mi < 4; ++mi)
#pragma unroll
            for (int reg = 0; reg < 4; ++reg) {
                int row = m0 + (wm * 4 + mi) * 16 + kq * 4 + reg;
                h_bf[(size_t)row * HID_ + col] = f2bf(gelu_exact(acc[mi][ni][reg] + bb));
            }
    }
}

// ---------------- fc2 GEMM (M=NHW,N=256,K=1024) + LN(1e-5) + gamma2 residual into t ----------------
// 64x256 tile, 4 waves split M (16 rows each, full 256 cols -> in-wave LN), BK=64.
__global__ __launch_bounds__(256) void k_fc2ln_mfma(const unsigned short* __restrict__ h_bf,
                                                    const unsigned short* __restrict__ fc2wT,
                                                    const float* __restrict__ fc2b,
                                                    const float* __restrict__ g2, const float* __restrict__ lg,
                                                    const float* __restrict__ lb, float* __restrict__ t) {
    __shared__ bf16x8 sA[512];    // chunk = ((mi*2+ksub)*64) + kq*16 + r  (mi<4)
    __shared__ bf16x8 sB[2048];   // chunk = ((ni*2+ksub)*64) + kq*16 + r  (ni<16)
    int tid = threadIdx.x;
    int wave = tid >> 6, lane = tid & 63;
    int r = lane & 15, kq = lane >> 4;
    int m0 = blockIdx.x * 64;

    f32x4 acc[16] = {};
#pragma unroll 1
    for (int kt = 0; kt < 16; ++kt) {
        int k0 = kt * 64;
        bf16x8 stA[2], stB[8];
#pragma unroll
        for (int j = 0; j < 2; ++j) {
            int c = j * 256 + tid;
            int q = c >> 6, ln = c & 63;
            int arow = (q >> 1) * 16 + (ln & 15);
            int cc   = (q & 1) * 4 + (ln >> 4);
            stA[j] = *(const bf16x8*)(h_bf + (size_t)(m0 + arow) * HID_ + k0 + cc * 8);
        }
#pragma unroll
        for (int j = 0; j < 8; ++j) {
            int c = j * 256 + tid;
            int q = c >> 6, ln = c & 63;
            int brow = (q >> 1) * 16 + (ln & 15);
            int cc   = (q & 1) * 4 + (ln >> 4);
            stB[j] = *(const bf16x8*)(fc2wT + (size_t)brow * HID_ + k0 + cc * 8);
        }
        if (kt) __syncthreads();
#pragma unroll
        for (int j = 0; j < 2; ++j) sA[j * 256 + tid] = stA[j];
#pragma unroll
        for (int j = 0; j < 8; ++j) sB[j * 256 + tid] = stB[j];
        __syncthreads();
#pragma unroll
        for (int ks = 0; ks < 2; ++ks) {
            bf16x8 a = sA[(wave * 2 + ks) * 64 + lane];
#pragma unroll
            for (int ni = 0; ni < 16; ++ni) {
                bf16x8 b = sB[(ni * 2 + ks) * 64 + lane];
                acc[ni] = __builtin_amdgcn_mfma_f32_16x16x32_bf16(a, b, acc[ni], 0, 0, 0);
            }
        }
    }
    // epilogue: bias, per-row LN over 256 cols (in-wave), gamma2 residual into t
    float bb[16], g2v[16], lgv[16], lbv[16];
#pragma unroll
    for (int ni = 0; ni < 16; ++ni) {
        int col = ni * 16 + r;
        bb[ni] = fc2b[col]; g2v[ni] = g2[col]; lgv[ni] = lg[col]; lbv[ni] = lb[col];
    }
#pragma unroll
    for (int ni = 0; ni < 16; ++ni)
#pragma unroll
        for (int reg = 0; reg < 4; ++reg) acc[ni][reg] += bb[ni];
#pragma unroll
    for (int reg = 0; reg < 4; ++reg) {
        float s1 = 0.f, s2 = 0.f;
#pragma unroll
        for (int ni = 0; ni < 16; ++ni) { float vv = acc[ni][reg]; s1 += vv; s2 += vv * vv; }
#pragma unroll
        for (int off = 1; off < 16; off <<= 1) { s1 += __shfl_xor(s1, off, 64); s2 += __shfl_xor(s2, off, 64); }
        float mu  = s1 * (1.f / C_);
        float var = fmaxf(s2 * (1.f / C_) - mu * mu, 0.f);
        float rs  = rsqrtf(var + 1e-5f);
        int row = m0 + wave * 16 + kq * 4 + reg;
        float* tr = t + (size_t)row * C_;
#pragma unroll
        for (int ni = 0; ni < 16; ++ni) {
            int col = ni * 16 + r;
            tr[col] += g2v[ni] * ((acc[ni][reg] - mu) * rs * lgv[ni] + lbv[ni]);
        }
    }
}

// ---------------- BN2 + input residual + ReLU -> out (NCHW) ----------------
__global__ __launch_bounds__(256) void k_final(const float* __restrict__ t, const float* __restrict__ x,
                                               const float* __restrict__ g, const float* __restrict__ b,
                                               const float* __restrict__ m, const float* __restrict__ v,
                                               float* __restrict__ out) {
    int i  = blockIdx.x * 256 + threadIdx.x;
    int hw = i % HW_;
    int r  = i / HW_;
    int c  = r & 255;
    int n  = r >> 8;
    float tv  = t[(size_t)(n * HW_ + hw) * C_ + c];
    float s   = rsqrtf(v[c] + 1e-5f);
    float val = (tv - m[c]) * (g[c] * s) + b[c] + x[i];
    out[i] = fmaxf(val, 0.f);
}

extern "C" void kernel_launch(void* const* d_in, const int* in_sizes, int n_in,
                              void* d_out, int out_size, void* d_ws, size_t ws_size,
                              hipStream_t stream) {
    const float* x      = (const float*)d_in[0];
    const float* conv1w = (const float*)d_in[1];
    const float* bn1g   = (const float*)d_in[2];
    const float* bn1b   = (const float*)d_in[3];
    const float* bn1m   = (const float*)d_in[4];
    const float* bn1v   = (const float*)d_in[5];
    const float* ln1g   = (const float*)d_in[6];
    const float* ln1b   = (const float*)d_in[7];
    const float* dww    = (const float*)d_in[8];
    const float* dwb    = (const float*)d_in[9];
    const float* dwlng  = (const float*)d_in[10];
    const float* dwlnb  = (const float*)d_in[11];
    const float* offw   = (const float*)d_in[12];
    const float* offb   = (const float*)d_in[13];
    const float* mskw   = (const float*)d_in[14];
    const float* mskb   = (const float*)d_in[15];
    const float* inpw   = (const float*)d_in[16];
    const float* inpb   = (const float*)d_in[17];
    const float* outpw  = (const float*)d_in[18];
    const float* outpb  = (const float*)d_in[19];
    const float* gamma1 = (const float*)d_in[20];
    const float* ln2g   = (const float*)d_in[21];
    const float* ln2b   = (const float*)d_in[22];
    const float* fc1w   = (const float*)d_in[23];
    const float* fc1b   = (const float*)d_in[24];
    const float* fc2w   = (const float*)d_in[25];
    const float* fc2b   = (const float*)d_in[26];
    const float* gamma2 = (const float*)d_in[27];
    const float* bn2g   = (const float*)d_in[28];
    const float* bn2b   = (const float*)d_in[29];
    const float* bn2m   = (const float*)d_in[30];
    const float* bn2v   = (const float*)d_in[31];
    float* out = (float*)d_out;

    // ---- workspace layout (dead-by-MLP region first, aliased by h_bf) ----
    float* ws    = (float*)d_ws;
    float* xproj = ws;                                    // [NHW][256] f32   (dead after core)
    float* offo  = xproj + (size_t)NHW_ * C_;             // [NHW][144] f32   (dead after core)
    float* msko  = offo  + (size_t)NHW_ * 144;            // [NHW][72]  f32   (dead after core)
    unsigned short* x1_bf = (unsigned short*)(msko + (size_t)NHW_ * 72);   // [NHW][256] (dead after offmask)
    unsigned short* scr   = x1_bf + (size_t)NHW_ * C_;    // xpad / core_bf alias
    float* t     = (float*)(scr + (size_t)N_ * XP_H * XP_W * C_);          // [NHW][256] f32
    float* omb   = t + (size_t)NHW_ * C_;                 // [256] f32
    unsigned short* t_bf  = (unsigned short*)(omb + 256); // [NHW][256]
    unsigned short* wTT   = t_bf  + (size_t)NHW_ * C_;    // [9][256][256]
    unsigned short* inpwT = wTT   + (size_t)9 * C_ * C_;  // [256][256]
    unsigned short* outpwT= inpwT + (size_t)C_ * C_;
    unsigned short* fc1wT = outpwT+ (size_t)C_ * C_;      // [1024][256]
    unsigned short* fc2wT = fc1wT + (size_t)HID_ * C_;    // [256][1024]
    unsigned short* omT   = fc2wT + (size_t)C_ * HID_;    // [256][256]
    unsigned short* xpad    = scr;
    unsigned short* core_bf = scr;
    unsigned short* h_bf    = (unsigned short*)xproj;     // [NHW][1024] aliases xproj..x1_bf (51.4MB < 60.2MB)

    hipMemsetAsync(xpad, 0, (size_t)N_ * XP_H * XP_W * C_ * sizeof(unsigned short), stream);
    k_prep_xpad<<<N_ * H_, 256, 0, stream>>>(x, xpad);
    k_prep_wTT <<<2304,    256, 0, stream>>>(conv1w, wTT);
    k_prep_sqT <<<256,     256, 0, stream>>>(inpw, inpwT);
    k_prep_sqT <<<256,     256, 0, stream>>>(outpw, outpwT);
    k_prep_fc1T<<<1024,    256, 0, stream>>>(fc1w, fc1wT);
    k_prep_fc2T<<<256,     256, 0, stream>>>(fc2w, fc2wT);
    k_prep_om  <<<256,     256, 0, stream>>>(offw, offb, mskw, mskb, omT, omb);

    k_conv1_mfma  <<<NHW_ / 32, 256, 0, stream>>>(xpad, wTT, bn1g, bn1b, bn1m, bn1v, t, t_bf);
    k_inproj_mfma <<<NHW_ / 32, 256, 0, stream>>>(t_bf, inpwT, inpb, xproj);
    k_dw          <<<NHW_,      256, 0, stream>>>(t, dww, dwb, dwlng, dwlnb, x1_bf);
    k_offmask_mfma<<<NHW_ / 32, 256, 0, stream>>>(x1_bf, omT, omb, offo, msko);
    k_core        <<<NHW_,      256, 0, stream>>>(xproj, offo, msko, core_bf);
    k_outproj_mfma<<<NHW_ / 32, 256, 0, stream>>>(core_bf, outpwT, outpb, gamma1, ln1g, ln1b, t, t_bf);
    k_fc1_mfma    <<<(NHW_ / 128) * 4, 256, 0, stream>>>(t_bf, fc1wT, fc1b, h_bf);
    k_fc2ln_mfma  <<<NHW_ / 64, 256, 0, stream>>>(h_bf, fc2wT, fc2b, gamma2, ln2g, ln2b, t);
    k_final       <<<NHW_,      256, 0, stream>>>(t, x, bn2g, bn2b, bn2m, bn2v, out);
}

// Round 6
// 746.019 us; speedup vs baseline: 1.2013x; 1.2013x over previous
//
#include <hip/hip_runtime.h>
#include <cmath>

#define N_   8
#define H_   56
#define W_   56
#define C_   256
#define HW_  3136
#define NHW_ 25088
#define G_   8
#define GC_  32
#define P_   9
#define HID_ 1024
#define XP_H 58
#define XP_W 58

typedef __attribute__((ext_vector_type(8))) short bf16x8;
typedef __attribute__((ext_vector_type(4))) float f32x4;

#define GLOAD_LDS16(g, l) __builtin_amdgcn_global_load_lds( \
    (const __attribute__((address_space(1))) void*)(g), \
    (__attribute__((address_space(3))) void*)(l), 16, 0, 0)

__device__ __forceinline__ unsigned short f2bf(float f) {
    unsigned u = __float_as_uint(f);
    u += 0x7FFF + ((u >> 16) & 1);   // round-to-nearest-even
    return (unsigned short)(u >> 16);
}

__device__ __forceinline__ float gelu_exact(float v) {
    return 0.5f * v * (1.f + erff(v * 0.70710678118654752f));
}

// ---------------- block-wide sum of (a,b) over 256 threads ----------------
__device__ __forceinline__ float2 block_sum2(float a, float b, float* sm) {
    int lane = threadIdx.x & 63;
    int wid  = threadIdx.x >> 6;
#pragma unroll
    for (int off = 32; off > 0; off >>= 1) {
        a += __shfl_down(a, off, 64);
        b += __shfl_down(b, off, 64);
    }
    if (lane == 0) { sm[wid] = a; sm[wid + 4] = b; }
    __syncthreads();
    float ra = sm[0] + sm[1] + sm[2] + sm[3];
    float rb = sm[4] + sm[5] + sm[6] + sm[7];
    __syncthreads();
    return make_float2(ra, rb);
}

// ---------------- x (NCHW fp32) -> xpad (N,58,58,256 bf16), border pre-zeroed ----------------
__global__ __launch_bounds__(256) void k_prep_xpad(const float* __restrict__ x, unsigned short* __restrict__ xpad) {
    int nh = blockIdx.x;                   // N_*H_ = 448
    int n = nh / H_, h = nh - n * H_;
    int c = threadIdx.x;
    const float* xr = x + ((size_t)(n * C_ + c)) * HW_ + h * W_;
    unsigned short* orow = xpad + ((size_t)((n * XP_H + h + 1) * XP_W + 1)) * C_ + c;
    for (int w = 0; w < W_; ++w) orow[(size_t)w * C_] = f2bf(xr[w]);
}

// ---------------- conv1 weights [co][ci][3][3] -> wTT [kk][co][ci] bf16 ----------------
__global__ __launch_bounds__(256) void k_prep_wTT(const float* __restrict__ w, unsigned short* __restrict__ wTT) {
    int i  = blockIdx.x * 256 + threadIdx.x;   // 9*256*256
    int ci = i & 255;
    int r  = i >> 8;
    int co = r & 255;
    int kk = r >> 8;
    wTT[i] = f2bf(w[(co * 256 + ci) * 9 + kk]);
}

// ---------------- square 256x256 weight -> W^T bf16 [n][k] ----------------
__global__ __launch_bounds__(256) void k_prep_sqT(const float* __restrict__ src, unsigned short* __restrict__ dst) {
    int n = blockIdx.x, k = threadIdx.x;
    dst[n * C_ + k] = f2bf(src[k * C_ + n]);
}

// ---------------- fc1 [256][1024] -> [1024][256] bf16 ----------------
__global__ __launch_bounds__(256) void k_prep_fc1T(const float* __restrict__ src, unsigned short* __restrict__ dst) {
    int n = blockIdx.x, k = threadIdx.x;
    dst[(size_t)n * C_ + k] = f2bf(src[(size_t)k * HID_ + n]);
}

// ---------------- fc2 [1024][256] -> [256][1024] bf16 ----------------
__global__ __launch_bounds__(256) void k_prep_fc2T(const float* __restrict__ src, unsigned short* __restrict__ dst) {
    int n = blockIdx.x, k0 = threadIdx.x;
#pragma unroll
    for (int q = 0; q < 4; ++q) {
        int k = q * 256 + k0;
        dst[(size_t)n * HID_ + k] = f2bf(src[(size_t)k * C_ + n]);
    }
}

// ---------------- offw[256][144] + mskw[256][72] -> omT [256][256] bf16 (+ omb) ----------------
__global__ __launch_bounds__(256) void k_prep_om(const float* __restrict__ offw, const float* __restrict__ offb,
                                                 const float* __restrict__ mskw, const float* __restrict__ mskb,
                                                 unsigned short* __restrict__ omT, float* __restrict__ omb) {
    int n = blockIdx.x, k = threadIdx.x;
    float v = 0.f;
    if (n < 144)      v = offw[k * 144 + n];
    else if (n < 216) v = mskw[k * 72 + (n - 144)];
    omT[n * C_ + k] = f2bf(v);
    if (k == 0) omb[n] = (n < 144) ? offb[n] : (n < 216 ? mskb[n - 144] : 0.f);
}

// ---------------- conv1 via MFMA implicit GEMM + BN1 + ReLU -> t (f32) + t_bf ----------------
__global__ __launch_bounds__(256) void k_conv1_mfma(const unsigned short* __restrict__ xpad,
                                                    const unsigned short* __restrict__ wTT,
                                                    const float* __restrict__ g, const float* __restrict__ b,
                                                    const float* __restrict__ m, const float* __restrict__ v,
                                                    float* __restrict__ t, unsigned short* __restrict__ t_bf) {
    int wave = threadIdx.x >> 6;
    int lane = threadIdx.x & 63;
    int r    = lane & 15;
    int kq   = lane >> 4;
    int co0  = wave * 64;
    int p0   = blockIdx.x * 32;

    size_t abase[2];
#pragma unroll
    for (int mi = 0; mi < 2; ++mi) {
        int pix = p0 + mi * 16 + r;
        int n = pix / HW_, hw = pix - n * HW_;
        int h = hw / W_,  w = hw - h * W_;
        abase[mi] = ((size_t)((n * XP_H + h) * XP_W + w)) * C_ + kq * 8;
    }

    f32x4 acc[2][4] = {};
#pragma unroll 1
    for (int tap = 0; tap < 9; ++tap) {
        int kh = tap / 3, kw = tap - kh * 3;
        size_t aoff = (size_t)(kh * XP_W + kw) * C_;
        const unsigned short* bp = wTT + ((size_t)(tap * C_) + co0 + r) * C_ + kq * 8;
        const unsigned short* a0p = xpad + abase[0] + aoff;
        const unsigned short* a1p = xpad + abase[1] + aoff;
#pragma unroll
        for (int ks = 0; ks < 8; ++ks) {
            bf16x8 a0 = *(const bf16x8*)(a0p + ks * 32);
            bf16x8 a1 = *(const bf16x8*)(a1p + ks * 32);
            bf16x8 b0 = *(const bf16x8*)(bp + 0 * 16 * C_ + ks * 32);
            bf16x8 b1 = *(const bf16x8*)(bp + 1 * 16 * C_ + ks * 32);
            bf16x8 b2 = *(const bf16x8*)(bp + 2 * 16 * C_ + ks * 32);
            bf16x8 b3 = *(const bf16x8*)(bp + 3 * 16 * C_ + ks * 32);
            acc[0][0] = __builtin_amdgcn_mfma_f32_16x16x32_bf16(a0, b0, acc[0][0], 0, 0, 0);
            acc[0][1] = __builtin_amdgcn_mfma_f32_16x16x32_bf16(a0, b1, acc[0][1], 0, 0, 0);
            acc[0][2] = __builtin_amdgcn_mfma_f32_16x16x32_bf16(a0, b2, acc[0][2], 0, 0, 0);
            acc[0][3] = __builtin_amdgcn_mfma_f32_16x16x32_bf16(a0, b3, acc[0][3], 0, 0, 0);
            acc[1][0] = __builtin_amdgcn_mfma_f32_16x16x32_bf16(a1, b0, acc[1][0], 0, 0, 0);
            acc[1][1] = __builtin_amdgcn_mfma_f32_16x16x32_bf16(a1, b1, acc[1][1], 0, 0, 0);
            acc[1][2] = __builtin_amdgcn_mfma_f32_16x16x32_bf16(a1, b2, acc[1][2], 0, 0, 0);
            acc[1][3] = __builtin_amdgcn_mfma_f32_16x16x32_bf16(a1, b3, acc[1][3], 0, 0, 0);
        }
    }

#pragma unroll
    for (int ni = 0; ni < 4; ++ni) {
        int co = co0 + ni * 16 + r;
        float sc = g[co] * rsqrtf(v[co] + 1e-5f);
        float sh = b[co] - m[co] * sc;
#pragma unroll
        for (int mi = 0; mi < 2; ++mi) {
#pragma unroll
            for (int reg = 0; reg < 4; ++reg) {
                int pix = p0 + mi * 16 + kq * 4 + reg;
                float val = fmaxf(acc[mi][ni][reg] * sc + sh, 0.f);
                size_t idx = (size_t)pix * C_ + co;
                t[idx] = val;
                t_bf[idx] = f2bf(val);
            }
        }
    }
}

// ---------------- input proj via MFMA: xproj = t_bf @ inpwT^T + b (f32 out) ----------------
__global__ __launch_bounds__(256) void k_inproj_mfma(const unsigned short* __restrict__ t_bf,
                                                     const unsigned short* __restrict__ inpwT,
                                                     const float* __restrict__ bias,
                                                     float* __restrict__ xproj) {
    int wave = threadIdx.x >> 6, lane = threadIdx.x & 63;
    int r = lane & 15, kq = lane >> 4;
    int p0 = blockIdx.x * 32, co0 = wave * 64;
    f32x4 acc[2][4] = {};
#pragma unroll 1
    for (int ks = 0; ks < 8; ++ks) {
        bf16x8 a0 = *(const bf16x8*)(t_bf + (size_t)(p0 + r) * C_ + ks * 32 + kq * 8);
        bf16x8 a1 = *(const bf16x8*)(t_bf + (size_t)(p0 + 16 + r) * C_ + ks * 32 + kq * 8);
        const unsigned short* bp = inpwT + (size_t)(co0 + r) * C_ + ks * 32 + kq * 8;
#pragma unroll
        for (int ni = 0; ni < 4; ++ni) {
            bf16x8 b = *(const bf16x8*)(bp + (size_t)ni * 16 * C_);
            acc[0][ni] = __builtin_amdgcn_mfma_f32_16x16x32_bf16(a0, b, acc[0][ni], 0, 0, 0);
            acc[1][ni] = __builtin_amdgcn_mfma_f32_16x16x32_bf16(a1, b, acc[1][ni], 0, 0, 0);
        }
    }
#pragma unroll
    for (int ni = 0; ni < 4; ++ni) {
        int col = co0 + ni * 16 + r;
        float bb = bias[col];
#pragma unroll
        for (int mi = 0; mi < 2; ++mi)
#pragma unroll
            for (int reg = 0; reg < 4; ++reg) {
                int pix = p0 + mi * 16 + kq * 4 + reg;
                xproj[(size_t)pix * C_ + col] = acc[mi][ni][reg] + bb;
            }
    }
}

// ---------------- depthwise 3x3 + LN(1e-6) + exact GELU -> x1_bf ----------------
__global__ __launch_bounds__(256) void k_dw(const float* __restrict__ t, const float* __restrict__ dww,
                                            const float* __restrict__ dwb, const float* __restrict__ lg,
                                            const float* __restrict__ lb, unsigned short* __restrict__ x1_bf) {
    __shared__ float sm[8];
    int pix = blockIdx.x;
    int n = pix / HW_, hw = pix - n * HW_;
    int h = hw / W_,  w = hw - h * W_;
    int c = threadIdx.x;
    float acc = dwb[c];
#pragma unroll
    for (int kh = 0; kh < 3; ++kh) {
        int y = h + kh - 1;
        if ((unsigned)y >= H_) continue;
#pragma unroll
        for (int kw = 0; kw < 3; ++kw) {
            int xx = w + kw - 1;
            if ((unsigned)xx >= W_) continue;
            acc = fmaf(t[(size_t)(n * HW_ + y * W_ + xx) * C_ + c], dww[(kh * 3 + kw) * C_ + c], acc);
        }
    }
    float2 r  = block_sum2(acc, acc * acc, sm);
    float mu  = r.x * (1.f / C_);
    float var = fmaxf(r.y * (1.f / C_) - mu * mu, 0.f);
    float rs  = rsqrtf(var + 1e-6f);
    float val = (acc - mu) * rs * lg[c] + lb[c];
    x1_bf[(size_t)pix * C_ + c] = f2bf(gelu_exact(val));
}

// ---------------- offset+mask via MFMA (N=256: 144 off | 72 msk | 40 pad) + softmax ----------------
__global__ __launch_bounds__(256) void k_offmask_mfma(const unsigned short* __restrict__ x1_bf,
                                                      const unsigned short* __restrict__ omT,
                                                      const float* __restrict__ omb,
                                                      float* __restrict__ offo, float* __restrict__ msko) {
    __shared__ float som[32][225];
    int wave = threadIdx.x >> 6, lane = threadIdx.x & 63;
    int r = lane & 15, kq = lane >> 4;
    int p0 = blockIdx.x * 32, co0 = wave * 64;
    f32x4 acc[2][4] = {};
#pragma unroll 1
    for (int ks = 0; ks < 8; ++ks) {
        bf16x8 a0 = *(const bf16x8*)(x1_bf + (size_t)(p0 + r) * C_ + ks * 32 + kq * 8);
        bf16x8 a1 = *(const bf16x8*)(x1_bf + (size_t)(p0 + 16 + r) * C_ + ks * 32 + kq * 8);
        const unsigned short* bp = omT + (size_t)(co0 + r) * C_ + ks * 32 + kq * 8;
#pragma unroll
        for (int ni = 0; ni < 4; ++ni) {
            bf16x8 b = *(const bf16x8*)(bp + (size_t)ni * 16 * C_);
            acc[0][ni] = __builtin_amdgcn_mfma_f32_16x16x32_bf16(a0, b, acc[0][ni], 0, 0, 0);
            acc[1][ni] = __builtin_amdgcn_mfma_f32_16x16x32_bf16(a1, b, acc[1][ni], 0, 0, 0);
        }
    }
#pragma unroll
    for (int ni = 0; ni < 4; ++ni) {
        int col = co0 + ni * 16 + r;
        if (col < 216) {
            float bb = omb[col];
#pragma unroll
            for (int mi = 0; mi < 2; ++mi)
#pragma unroll
                for (int reg = 0; reg < 4; ++reg)
                    som[mi * 16 + kq * 4 + reg][col] = acc[mi][ni][reg] + bb;
        }
    }
    __syncthreads();
    int tid = threadIdx.x;
#pragma unroll
    for (int i = 0; i < 18; ++i) {
        int j = i * 256 + tid;          // 32*144 = 4608
        int px = j / 144, col = j - px * 144;
        offo[(size_t)(p0 + px) * 144 + col] = som[px][col];
    }
    int px = tid >> 3, g = tid & 7;
    float mx = -1e30f;
#pragma unroll
    for (int p = 0; p < 9; ++p) mx = fmaxf(mx, som[px][144 + g * 9 + p]);
    float e[9], s = 0.f;
#pragma unroll
    for (int p = 0; p < 9; ++p) { e[p] = expf(som[px][144 + g * 9 + p] - mx); s += e[p]; }
    float inv = 1.f / s;
#pragma unroll
    for (int p = 0; p < 9; ++p) msko[(size_t)(p0 + px) * 72 + g * 9 + p] = e[p] * inv;
}

// ---------------- DCNv3 deformable sampling core -> core_bf ----------------
__global__ __launch_bounds__(256) void k_core(const float* __restrict__ xp,
                                              const float* __restrict__ offo, const float* __restrict__ msko,
                                              unsigned short* __restrict__ core_bf) {
    int pix = blockIdx.x;
    int n = pix / HW_, hw = pix - n * HW_;
    int h = hw / W_,  w = hw - h * W_;
    int g  = threadIdx.x >> 5;
    int cc = threadIdx.x & 31;
    const float* op = offo + (size_t)pix * 144 + g * 18;
    const float* mp = msko + (size_t)pix * 72 + g * 9;
    const float* xg = xp + (size_t)n * HW_ * C_ + g * GC_ + cc;
    float acc = 0.f;
#pragma unroll
    for (int p = 0; p < 9; ++p) {
        float gx = (float)(w + (p / 3)) + op[p * 2];
        float gy = (float)(h + (p % 3)) + op[p * 2 + 1];
        float fx = floorf(gx), fy = floorf(gy);
        float wx = gx - fx,   wy = gy - fy;
        int ix = (int)fx - 1, iy = (int)fy - 1;
        float v00 = 0.f, v10 = 0.f, v01 = 0.f, v11 = 0.f;
        bool x0ok = (unsigned)ix < W_, x1ok = (unsigned)(ix + 1) < W_;
        bool y0ok = (unsigned)iy < H_, y1ok = (unsigned)(iy + 1) < H_;
        if (y0ok) {
            const float* rr = xg + (size_t)(iy * W_) * C_;
            if (x0ok) v00 = rr[(size_t)ix * C_];
            if (x1ok) v10 = rr[(size_t)(ix + 1) * C_];
        }
        if (y1ok) {
            const float* rr = xg + (size_t)((iy + 1) * W_) * C_;
            if (x0ok) v01 = rr[(size_t)ix * C_];
            if (x1ok) v11 = rr[(size_t)(ix + 1) * C_];
        }
        float sval = (v00 * (1.f - wx) + v10 * wx) * (1.f - wy)
                   + (v01 * (1.f - wx) + v11 * wx) * wy;
        acc = fmaf(mp[p], sval, acc);
    }
    core_bf[(size_t)pix * C_ + threadIdx.x] = f2bf(acc);
}

// ---------------- output proj MFMA + LN(1e-5) + gamma1 residual -> t, t_bf ----------------
__global__ __launch_bounds__(256) void k_outproj_mfma(const unsigned short* __restrict__ core_bf,
                                                      const unsigned short* __restrict__ outpwT,
                                                      const float* __restrict__ bo,
                                                      const float* __restrict__ g1, const float* __restrict__ lg,
                                                      const float* __restrict__ lb,
                                                      float* __restrict__ t, unsigned short* __restrict__ t_bf) {
    __shared__ float sd[32][260];
    int wave = threadIdx.x >> 6, lane = threadIdx.x & 63;
    int r = lane & 15, kq = lane >> 4;
    int p0 = blockIdx.x * 32, co0 = wave * 64;
    f32x4 acc[2][4] = {};
#pragma unroll 1
    for (int ks = 0; ks < 8; ++ks) {
        bf16x8 a0 = *(const bf16x8*)(core_bf + (size_t)(p0 + r) * C_ + ks * 32 + kq * 8);
        bf16x8 a1 = *(const bf16x8*)(core_bf + (size_t)(p0 + 16 + r) * C_ + ks * 32 + kq * 8);
        const unsigned short* bp = outpwT + (size_t)(co0 + r) * C_ + ks * 32 + kq * 8;
#pragma unroll
        for (int ni = 0; ni < 4; ++ni) {
            bf16x8 b = *(const bf16x8*)(bp + (size_t)ni * 16 * C_);
            acc[0][ni] = __builtin_amdgcn_mfma_f32_16x16x32_bf16(a0, b, acc[0][ni], 0, 0, 0);
            acc[1][ni] = __builtin_amdgcn_mfma_f32_16x16x32_bf16(a1, b, acc[1][ni], 0, 0, 0);
        }
    }
#pragma unroll
    for (int ni = 0; ni < 4; ++ni) {
        int col = co0 + ni * 16 + r;
        float bb = bo[col];
#pragma unroll
        for (int mi = 0; mi < 2; ++mi)
#pragma unroll
            for (int reg = 0; reg < 4; ++reg)
                sd[mi * 16 + kq * 4 + reg][col] = acc[mi][ni][reg] + bb;
    }
    __syncthreads();
    int px = threadIdx.x >> 3, sub = threadIdx.x & 7;
    float s1 = 0.f, s2 = 0.f;
#pragma unroll
    for (int i = 0; i < 8; ++i) {
        float4 vv = *(const float4*)&sd[px][sub * 32 + i * 4];
        s1 += vv.x + vv.y + vv.z + vv.w;
        s2 += vv.x * vv.x + vv.y * vv.y + vv.z * vv.z + vv.w * vv.w;
    }
#pragma unroll
    for (int off = 1; off < 8; off <<= 1) { s1 += __shfl_xor(s1, off, 64); s2 += __shfl_xor(s2, off, 64); }
    float mu  = s1 * (1.f / C_);
    float var = fmaxf(s2 * (1.f / C_) - mu * mu, 0.f);
    float rs  = rsqrtf(var + 1e-5f);
#pragma unroll
    for (int i = 0; i < 32; ++i) {
        int col = sub * 32 + i;
        size_t idx = (size_t)(p0 + px) * C_ + col;
        float tn = t[idx] + g1[col] * ((sd[px][col] - mu) * rs * lg[col] + lb[col]);
        t[idx] = tn;
        t_bf[idx] = f2bf(tn);
    }
}

// ---------------- fc1 GEMM (M=NHW,N=1024,K=256) + GELU -> h_bf ----------------
// 128x128 tile, 4 waves (2x2), BK=64; async global_load_lds into fragment-major chunks;
// output staged via padded LDS for coalesced 16B stores.
__global__ __launch_bounds__(256) void k_fc1_mfma(const unsigned short* __restrict__ t_bf,
                                                  const unsigned short* __restrict__ fc1wT,
                                                  const float* __restrict__ fc1b,
                                                  unsigned short* __restrict__ h_bf) {
    __shared__ __align__(16) unsigned char smem[34816];   // staging 32KB; out 128*136*2=34816B
    unsigned short* sm16 = (unsigned short*)smem;
    bf16x8* sA = (bf16x8*)smem;                 // 16 chunks * 64
    bf16x8* sB = (bf16x8*)(smem + 16384);       // 16 chunks * 64
    int tid = threadIdx.x;
    int wave = tid >> 6, lane = tid & 63;
    int r = lane & 15, kq = lane >> 4;
    int mt = blockIdx.x >> 3, nt = blockIdx.x & 7;
    int m0 = mt * 128, n0 = nt * 128;
    int wm = wave & 1, wn = wave >> 1;

    f32x4 acc[4][4] = {};
#pragma unroll 1
    for (int kt = 0; kt < 4; ++kt) {
        int k0 = kt * 64;
        if (kt) __syncthreads();               // previous tile's reads done
#pragma unroll
        for (int i = 0; i < 4; ++i) {          // A chunks q = wave*4+i
            int q = wave * 4 + i;
            int row = m0 + (q >> 1) * 16 + r;
            int cc  = (q & 1) * 4 + kq;
            GLOAD_LDS16(t_bf + (size_t)row * C_ + k0 + cc * 8, sm16 + q * 512);
        }
#pragma unroll
        for (int i = 0; i < 4; ++i) {          // B chunks q = wave*4+i
            int q = wave * 4 + i;
            int nrow = n0 + (q >> 1) * 16 + r;
            int cc   = (q & 1) * 4 + kq;
            GLOAD_LDS16(fc1wT + (size_t)nrow * C_ + k0 + cc * 8, sm16 + 8192 + q * 512);
        }
        __syncthreads();                       // drains vmcnt before barrier
#pragma unroll
        for (int ks = 0; ks < 2; ++ks) {
            bf16x8 af[4], bfr[4];
#pragma unroll
            for (int mi = 0; mi < 4; ++mi) af[mi]  = sA[((wm * 4 + mi) * 2 + ks) * 64 + lane];
#pragma unroll
            for (int ni = 0; ni < 4; ++ni) bfr[ni] = sB[((wn * 4 + ni) * 2 + ks) * 64 + lane];
#pragma unroll
            for (int mi = 0; mi < 4; ++mi)
#pragma unroll
                for (int ni = 0; ni < 4; ++ni)
                    acc[mi][ni] = __builtin_amdgcn_mfma_f32_16x16x32_bf16(af[mi], bfr[ni], acc[mi][ni], 0, 0, 0);
        }
    }
    __syncthreads();                           // all ds_reads done before out-staging overwrites
#pragma unroll
    for (int ni = 0; ni < 4; ++ni) {
        int col = (wn * 4 + ni) * 16 + r;
        float bb = fc1b[n0 + col];
#pragma unroll
        for (int mi = 0; mi < 4; ++mi)
#pragma unroll
            for (int reg = 0; reg < 4; ++reg) {
                int row = (wm * 4 + mi) * 16 + kq * 4 + reg;
                sm16[row * 136 + col] = f2bf(gelu_exact(acc[mi][ni][reg] + bb));
            }
    }
    __syncthreads();
    int trow = tid >> 1, thalf = tid & 1;
    const unsigned short* src = sm16 + trow * 136 + thalf * 64;
    unsigned short* dst = h_bf + (size_t)(m0 + trow) * HID_ + n0 + thalf * 64;
#pragma unroll
    for (int j = 0; j < 8; ++j)
        *(bf16x8*)(dst + j * 8) = *(const bf16x8*)(src + j * 8);
}

// ---------------- fc2 GEMM (M=NHW,N=256,K=1024) + LN(1e-5) + gamma2 residual into t ----------------
// 64x256 tile, 4 waves split M (16 rows each, full 256 cols -> in-wave LN), BK=64, async staging.
__global__ __launch_bounds__(256) void k_fc2ln_mfma(const unsigned short* __restrict__ h_bf,
                                                    const unsigned short* __restrict__ fc2wT,
                                                    const float* __restrict__ fc2b,
                                                    const float* __restrict__ g2, const float* __restrict__ lg,
                                                    const float* __restrict__ lb, float* __restrict__ t) {
    __shared__ __align__(16) unsigned char smem[40960];   // A 8KB + B 32KB
    unsigned short* sm16 = (unsigned short*)smem;
    bf16x8* sA = (bf16x8*)smem;                 // 8 chunks * 64
    bf16x8* sB = (bf16x8*)(smem + 8192);        // 32 chunks * 64
    int tid = threadIdx.x;
    int wave = tid >> 6, lane = tid & 63;
    int r = lane & 15, kq = lane >> 4;
    int m0 = blockIdx.x * 64;

    f32x4 acc[16] = {};
#pragma unroll 1
    for (int kt = 0; kt < 16; ++kt) {
        int k0 = kt * 64;
        if (kt) __syncthreads();
#pragma unroll
        for (int i = 0; i < 2; ++i) {          // A chunks q = wave*2+i  (mfrag = q>>1 = wave)
            int q = wave * 2 + i;
            int row = m0 + (q >> 1) * 16 + r;
            int cc  = (q & 1) * 4 + kq;
            GLOAD_LDS16(h_bf + (size_t)row * HID_ + k0 + cc * 8, sm16 + q * 512);
        }
#pragma unroll
        for (int i = 0; i < 8; ++i) {          // B chunks q = wave*8+i
            int q = wave * 8 + i;
            int nrow = (q >> 1) * 16 + r;
            int cc   = (q & 1) * 4 + kq;
            GLOAD_LDS16(fc2wT + (size_t)nrow * HID_ + k0 + cc * 8, sm16 + 4096 + q * 512);
        }
        __syncthreads();
#pragma unroll
        for (int ks = 0; ks < 2; ++ks) {
            bf16x8 a = sA[(wave * 2 + ks) * 64 + lane];
#pragma unroll
            for (int ni = 0; ni < 16; ++ni) {
                bf16x8 b = sB[(ni * 2 + ks) * 64 + lane];
                acc[ni] = __builtin_amdgcn_mfma_f32_16x16x32_bf16(a, b, acc[ni], 0, 0, 0);
            }
        }
    }
    // epilogue: bias, per-row LN over 256 cols (in-wave), gamma2 residual into t
    float bb[16], g2v[16], lgv[16], lbv[16];
#pragma unroll
    for (int ni = 0; ni < 16; ++ni) {
        int col = ni * 16 + r;
        bb[ni] = fc2b[col]; g2v[ni] = g2[col]; lgv[ni] = lg[col]; lbv[ni] = lb[col];
    }
#pragma unroll
    for (int ni = 0; ni < 16; ++ni)
#pragma unroll
        for (int reg = 0; reg < 4; ++reg) acc[ni][reg] += bb[ni];
#pragma unroll
    for (int reg = 0; reg < 4; ++reg) {
        float s1 = 0.f, s2 = 0.f;
#pragma unroll
        for (int ni = 0; ni < 16; ++ni) { float vv = acc[ni][reg]; s1 += vv; s2 += vv * vv; }
#pragma unroll
        for (int off = 1; off < 16; off <<= 1) { s1 += __shfl_xor(s1, off, 64); s2 += __shfl_xor(s2, off, 64); }
        float mu  = s1 * (1.f / C_);
        float var = fmaxf(s2 * (1.f / C_) - mu * mu, 0.f);
        float rs  = rsqrtf(var + 1e-5f);
        int row = m0 + wave * 16 + kq * 4 + reg;
        float* tr = t + (size_t)row * C_;
#pragma unroll
        for (int ni = 0; ni < 16; ++ni) {
            int col = ni * 16 + r;
            tr[col] += g2v[ni] * ((acc[ni][reg] - mu) * rs * lgv[ni] + lbv[ni]);
        }
    }
}

// ---------------- BN2 + input residual + ReLU -> out (NCHW) ----------------
__global__ __launch_bounds__(256) void k_final(const float* __restrict__ t, const float* __restrict__ x,
                                               const float* __restrict__ g, const float* __restrict__ b,
                                               const float* __restrict__ m, const float* __restrict__ v,
                                               float* __restrict__ out) {
    int i  = blockIdx.x * 256 + threadIdx.x;
    int hw = i % HW_;
    int r  = i / HW_;
    int c  = r & 255;
    int n  = r >> 8;
    float tv  = t[(size_t)(n * HW_ + hw) * C_ + c];
    float s   = rsqrtf(v[c] + 1e-5f);
    float val = (tv - m[c]) * (g[c] * s) + b[c] + x[i];
    out[i] = fmaxf(val, 0.f);
}

extern "C" void kernel_launch(void* const* d_in, const int* in_sizes, int n_in,
                              void* d_out, int out_size, void* d_ws, size_t ws_size,
                              hipStream_t stream) {
    const float* x      = (const float*)d_in[0];
    const float* conv1w = (const float*)d_in[1];
    const float* bn1g   = (const float*)d_in[2];
    const float* bn1b   = (const float*)d_in[3];
    const float* bn1m   = (const float*)d_in[4];
    const float* bn1v   = (const float*)d_in[5];
    const float* ln1g   = (const float*)d_in[6];
    const float* ln1b   = (const float*)d_in[7];
    const float* dww    = (const float*)d_in[8];
    const float* dwb    = (const float*)d_in[9];
    const float* dwlng  = (const float*)d_in[10];
    const float* dwlnb  = (const float*)d_in[11];
    const float* offw   = (const float*)d_in[12];
    const float* offb   = (const float*)d_in[13];
    const float* mskw   = (const float*)d_in[14];
    const float* mskb   = (const float*)d_in[15];
    const float* inpw   = (const float*)d_in[16];
    const float* inpb   = (const float*)d_in[17];
    const float* outpw  = (const float*)d_in[18];
    const float* outpb  = (const float*)d_in[19];
    const float* gamma1 = (const float*)d_in[20];
    const float* ln2g   = (const float*)d_in[21];
    const float* ln2b   = (const float*)d_in[22];
    const float* fc1w   = (const float*)d_in[23];
    const float* fc1b   = (const float*)d_in[24];
    const float* fc2w   = (const float*)d_in[25];
    const float* fc2b   = (const float*)d_in[26];
    const float* gamma2 = (const float*)d_in[27];
    const float* bn2g   = (const float*)d_in[28];
    const float* bn2b   = (const float*)d_in[29];
    const float* bn2m   = (const float*)d_in[30];
    const float* bn2v   = (const float*)d_in[31];
    float* out = (float*)d_out;

    // ---- workspace layout (dead-by-MLP region first, aliased by h_bf) ----
    float* ws    = (float*)d_ws;
    float* xproj = ws;                                    // [NHW][256] f32   (dead after core)
    float* offo  = xproj + (size_t)NHW_ * C_;             // [NHW][144] f32   (dead after core)
    float* msko  = offo  + (size_t)NHW_ * 144;            // [NHW][72]  f32   (dead after core)
    unsigned short* x1_bf = (unsigned short*)(msko + (size_t)NHW_ * 72);   // [NHW][256] (dead after offmask)
    unsigned short* scr   = x1_bf + (size_t)NHW_ * C_;    // xpad / core_bf alias
    float* t     = (float*)(scr + (size_t)N_ * XP_H * XP_W * C_);          // [NHW][256] f32
    float* omb   = t + (size_t)NHW_ * C_;                 // [256] f32
    unsigned short* t_bf  = (unsigned short*)(omb + 256); // [NHW][256]
    unsigned short* wTT   = t_bf  + (size_t)NHW_ * C_;    // [9][256][256]
    unsigned short* inpwT = wTT   + (size_t)9 * C_ * C_;  // [256][256]
    unsigned short* outpwT= inpwT + (size_t)C_ * C_;
    unsigned short* fc1wT = outpwT+ (size_t)C_ * C_;      // [1024][256]
    unsigned short* fc2wT = fc1wT + (size_t)HID_ * C_;    // [256][1024]
    unsigned short* omT   = fc2wT + (size_t)C_ * HID_;    // [256][256]
    unsigned short* xpad    = scr;
    unsigned short* core_bf = scr;
    unsigned short* h_bf    = (unsigned short*)xproj;     // [NHW][1024] aliases xproj..x1_bf (51.4MB < 60.2MB)

    hipMemsetAsync(xpad, 0, (size_t)N_ * XP_H * XP_W * C_ * sizeof(unsigned short), stream);
    k_prep_xpad<<<N_ * H_, 256, 0, stream>>>(x, xpad);
    k_prep_wTT <<<2304,    256, 0, stream>>>(conv1w, wTT);
    k_prep_sqT <<<256,     256, 0, stream>>>(inpw, inpwT);
    k_prep_sqT <<<256,     256, 0, stream>>>(outpw, outpwT);
    k_prep_fc1T<<<1024,    256, 0, stream>>>(fc1w, fc1wT);
    k_prep_fc2T<<<256,     256, 0, stream>>>(fc2w, fc2wT);
    k_prep_om  <<<256,     256, 0, stream>>>(offw, offb, mskw, mskb, omT, omb);

    k_conv1_mfma  <<<NHW_ / 32, 256, 0, stream>>>(xpad, wTT, bn1g, bn1b, bn1m, bn1v, t, t_bf);
    k_inproj_mfma <<<NHW_ / 32, 256, 0, stream>>>(t_bf, inpwT, inpb, xproj);
    k_dw          <<<NHW_,      256, 0, stream>>>(t, dww, dwb, dwlng, dwlnb, x1_bf);
    k_offmask_mfma<<<NHW_ / 32, 256, 0, stream>>>(x1_bf, omT, omb, offo, msko);
    k_core        <<<NHW_,      256, 0, stream>>>(xproj, offo, msko, core_bf);
    k_outproj_mfma<<<NHW_ / 32, 256, 0, stream>>>(core_bf, outpwT, outpb, gamma1, ln1g, ln1b, t, t_bf);
    k_fc1_mfma    <<<(NHW_ / 128) * 8, 256, 0, stream>>>(t_bf, fc1wT, fc1b, h_bf);
    k_fc2ln_mfma  <<<NHW_ / 64, 256, 0, stream>>>(h_bf, fc2wT, fc2b, gamma2, ln2g, ln2b, t);
    k_final       <<<NHW_,      256, 0, stream>>>(t, x, bn2g, bn2b, bn2m, bn2v, out);
}

// Round 7
// 657.762 us; speedup vs baseline: 1.3625x; 1.1342x over previous
//
#include <hip/hip_runtime.h>
#include <cmath>

#define N_   8
#define H_   56
#define W_   56
#define C_   256
#define HW_  3136
#define NHW_ 25088
#define G_   8
#define GC_  32
#define P_   9
#define HID_ 1024
#define XP_H 58
#define XP_W 58

typedef __attribute__((ext_vector_type(8))) short bf16x8;
typedef __attribute__((ext_vector_type(4))) float f32x4;

#define GLOAD_LDS16(g, l) __builtin_amdgcn_global_load_lds( \
    (const __attribute__((address_space(1))) void*)(g), \
    (__attribute__((address_space(3))) void*)(l), 16, 0, 0)

__device__ __forceinline__ unsigned short f2bf(float f) {
    unsigned u = __float_as_uint(f);
    u += 0x7FFF + ((u >> 16) & 1);   // round-to-nearest-even
    return (unsigned short)(u >> 16);
}

__device__ __forceinline__ float gelu_exact(float v) {
    return 0.5f * v * (1.f + erff(v * 0.70710678118654752f));
}

// ---------------- block-wide sum of (a,b) over 256 threads ----------------
__device__ __forceinline__ float2 block_sum2(float a, float b, float* sm) {
    int lane = threadIdx.x & 63;
    int wid  = threadIdx.x >> 6;
#pragma unroll
    for (int off = 32; off > 0; off >>= 1) {
        a += __shfl_down(a, off, 64);
        b += __shfl_down(b, off, 64);
    }
    if (lane == 0) { sm[wid] = a; sm[wid + 4] = b; }
    __syncthreads();
    float ra = sm[0] + sm[1] + sm[2] + sm[3];
    float rb = sm[4] + sm[5] + sm[6] + sm[7];
    __syncthreads();
    return make_float2(ra, rb);
}

// ---------------- x (NCHW fp32) -> xpad (N,58,58,256 bf16), border pre-zeroed ----------------
__global__ __launch_bounds__(256) void k_prep_xpad(const float* __restrict__ x, unsigned short* __restrict__ xpad) {
    int nh = blockIdx.x;                   // N_*H_ = 448
    int n = nh / H_, h = nh - n * H_;
    int c = threadIdx.x;
    const float* xr = x + ((size_t)(n * C_ + c)) * HW_ + h * W_;
    unsigned short* orow = xpad + ((size_t)((n * XP_H + h + 1) * XP_W + 1)) * C_ + c;
    for (int w = 0; w < W_; ++w) orow[(size_t)w * C_] = f2bf(xr[w]);
}

// ---------------- conv1 weights [co][ci][3][3] -> wTT [kk][co][ci] bf16 ----------------
__global__ __launch_bounds__(256) void k_prep_wTT(const float* __restrict__ w, unsigned short* __restrict__ wTT) {
    int i  = blockIdx.x * 256 + threadIdx.x;   // 9*256*256
    int ci = i & 255;
    int r  = i >> 8;
    int co = r & 255;
    int kk = r >> 8;
    wTT[i] = f2bf(w[(co * 256 + ci) * 9 + kk]);
}

// ---------------- square 256x256 weight -> W^T bf16 [n][k] ----------------
__global__ __launch_bounds__(256) void k_prep_sqT(const float* __restrict__ src, unsigned short* __restrict__ dst) {
    int n = blockIdx.x, k = threadIdx.x;
    dst[n * C_ + k] = f2bf(src[k * C_ + n]);
}

// ---------------- fc1 [256][1024] -> [1024][256] bf16 ----------------
__global__ __launch_bounds__(256) void k_prep_fc1T(const float* __restrict__ src, unsigned short* __restrict__ dst) {
    int n = blockIdx.x, k = threadIdx.x;
    dst[(size_t)n * C_ + k] = f2bf(src[(size_t)k * HID_ + n]);
}

// ---------------- fc2 [1024][256] -> [256][1024] bf16 ----------------
__global__ __launch_bounds__(256) void k_prep_fc2T(const float* __restrict__ src, unsigned short* __restrict__ dst) {
    int n = blockIdx.x, k0 = threadIdx.x;
#pragma unroll
    for (int q = 0; q < 4; ++q) {
        int k = q * 256 + k0;
        dst[(size_t)n * HID_ + k] = f2bf(src[(size_t)k * C_ + n]);
    }
}

// ---------------- offw[256][144] + mskw[256][72] -> omT [256][256] bf16 (+ omb) ----------------
__global__ __launch_bounds__(256) void k_prep_om(const float* __restrict__ offw, const float* __restrict__ offb,
                                                 const float* __restrict__ mskw, const float* __restrict__ mskb,
                                                 unsigned short* __restrict__ omT, float* __restrict__ omb) {
    int n = blockIdx.x, k = threadIdx.x;
    float v = 0.f;
    if (n < 144)      v = offw[k * 144 + n];
    else if (n < 216) v = mskw[k * 72 + (n - 144)];
    omT[n * C_ + k] = f2bf(v);
    if (k == 0) omb[n] = (n < 144) ? offb[n] : (n < 216 ? mskb[n - 144] : 0.f);
}

// ---------------- conv1 implicit GEMM: 64x128 tile, BK=64, async LDS staging ----------------
// K = 9 taps x 256; kt = tap*4 + ktk. Fragment-major LDS chunks (conflict-free b128).
__global__ __launch_bounds__(256) void k_conv1_mfma(const unsigned short* __restrict__ xpad,
                                                    const unsigned short* __restrict__ wTT,
                                                    const float* __restrict__ g, const float* __restrict__ b,
                                                    const float* __restrict__ m, const float* __restrict__ v,
                                                    float* __restrict__ t, unsigned short* __restrict__ t_bf) {
    __shared__ __align__(16) unsigned char smem[24576];   // A 8KB + B 16KB
    unsigned short* sm16 = (unsigned short*)smem;
    bf16x8* sA = (bf16x8*)smem;                 // 8 chunks * 64
    bf16x8* sB = (bf16x8*)(smem + 8192);        // 16 chunks * 64
    int tid = threadIdx.x;
    int wave = tid >> 6, lane = tid & 63;
    int r = lane & 15, kq = lane >> 4;
    int mt = blockIdx.x >> 1, nt = blockIdx.x & 1;
    int m0 = mt * 64, n0 = nt * 128;
    int wm = wave & 1, wn = wave >> 1;

    // per-lane A-row base: row = m0 + wave*16 + r  (A chunks q=wave*2+i cover these rows)
    int pix = m0 + wave * 16 + r;
    int n = pix / HW_, hw = pix - n * HW_;
    int h = hw / W_, w = hw - h * W_;
    size_t abase = ((size_t)((n * XP_H + h) * XP_W + w)) * C_;

    f32x4 acc[2][4] = {};
#pragma unroll 1
    for (int kt = 0; kt < 36; ++kt) {
        int tap = kt >> 2, ktk = kt & 3;
        int kh = tap / 3, kw = tap - kh * 3;
        int k0 = ktk * 64;
        const unsigned short* ap = xpad + abase + (size_t)(kh * XP_W + kw) * C_ + k0;
        if (kt) __syncthreads();               // prior tile's ds_reads done
#pragma unroll
        for (int i = 0; i < 2; ++i) {          // A chunks q = wave*2+i
            int q = wave * 2 + i;
            GLOAD_LDS16(ap + (i * 4 + kq) * 8, sm16 + q * 512);
        }
#pragma unroll
        for (int i = 0; i < 4; ++i) {          // B chunks q = wave*4+i
            int q = wave * 4 + i;
            int nrow = n0 + (q >> 1) * 16 + r;
            int cc   = (q & 1) * 4 + kq;
            GLOAD_LDS16(wTT + ((size_t)(tap * C_) + nrow) * C_ + k0 + cc * 8, sm16 + 4096 + q * 512);
        }
        __syncthreads();                       // drains vmcnt before barrier
#pragma unroll
        for (int ks = 0; ks < 2; ++ks) {
            bf16x8 af[2], bfr[4];
#pragma unroll
            for (int mi = 0; mi < 2; ++mi) af[mi]  = sA[((wm * 2 + mi) * 2 + ks) * 64 + lane];
#pragma unroll
            for (int ni = 0; ni < 4; ++ni) bfr[ni] = sB[((wn * 4 + ni) * 2 + ks) * 64 + lane];
#pragma unroll
            for (int mi = 0; mi < 2; ++mi)
#pragma unroll
                for (int ni = 0; ni < 4; ++ni)
                    acc[mi][ni] = __builtin_amdgcn_mfma_f32_16x16x32_bf16(af[mi], bfr[ni], acc[mi][ni], 0, 0, 0);
        }
    }

#pragma unroll
    for (int ni = 0; ni < 4; ++ni) {
        int co = n0 + (wn * 4 + ni) * 16 + r;
        float sc = g[co] * rsqrtf(v[co] + 1e-5f);
        float sh = b[co] - m[co] * sc;
#pragma unroll
        for (int mi = 0; mi < 2; ++mi) {
#pragma unroll
            for (int reg = 0; reg < 4; ++reg) {
                int po = m0 + (wm * 2 + mi) * 16 + kq * 4 + reg;
                float val = fmaxf(acc[mi][ni][reg] * sc + sh, 0.f);
                size_t idx = (size_t)po * C_ + co;
                t[idx] = val;
                t_bf[idx] = f2bf(val);
            }
        }
    }
}

// ---------------- input proj via MFMA: xproj = t_bf @ inpwT^T + b (f32 out) ----------------
__global__ __launch_bounds__(256) void k_inproj_mfma(const unsigned short* __restrict__ t_bf,
                                                     const unsigned short* __restrict__ inpwT,
                                                     const float* __restrict__ bias,
                                                     float* __restrict__ xproj) {
    int wave = threadIdx.x >> 6, lane = threadIdx.x & 63;
    int r = lane & 15, kq = lane >> 4;
    int p0 = blockIdx.x * 32, co0 = wave * 64;
    f32x4 acc[2][4] = {};
#pragma unroll 1
    for (int ks = 0; ks < 8; ++ks) {
        bf16x8 a0 = *(const bf16x8*)(t_bf + (size_t)(p0 + r) * C_ + ks * 32 + kq * 8);
        bf16x8 a1 = *(const bf16x8*)(t_bf + (size_t)(p0 + 16 + r) * C_ + ks * 32 + kq * 8);
        const unsigned short* bp = inpwT + (size_t)(co0 + r) * C_ + ks * 32 + kq * 8;
#pragma unroll
        for (int ni = 0; ni < 4; ++ni) {
            bf16x8 b = *(const bf16x8*)(bp + (size_t)ni * 16 * C_);
            acc[0][ni] = __builtin_amdgcn_mfma_f32_16x16x32_bf16(a0, b, acc[0][ni], 0, 0, 0);
            acc[1][ni] = __builtin_amdgcn_mfma_f32_16x16x32_bf16(a1, b, acc[1][ni], 0, 0, 0);
        }
    }
#pragma unroll
    for (int ni = 0; ni < 4; ++ni) {
        int col = co0 + ni * 16 + r;
        float bb = bias[col];
#pragma unroll
        for (int mi = 0; mi < 2; ++mi)
#pragma unroll
            for (int reg = 0; reg < 4; ++reg) {
                int pix = p0 + mi * 16 + kq * 4 + reg;
                xproj[(size_t)pix * C_ + col] = acc[mi][ni][reg] + bb;
            }
    }
}

// ---------------- depthwise 3x3 + LN(1e-6) + exact GELU -> x1_bf ----------------
__global__ __launch_bounds__(256) void k_dw(const float* __restrict__ t, const float* __restrict__ dww,
                                            const float* __restrict__ dwb, const float* __restrict__ lg,
                                            const float* __restrict__ lb, unsigned short* __restrict__ x1_bf) {
    __shared__ float sm[8];
    int pix = blockIdx.x;
    int n = pix / HW_, hw = pix - n * HW_;
    int h = hw / W_,  w = hw - h * W_;
    int c = threadIdx.x;
    float acc = dwb[c];
#pragma unroll
    for (int kh = 0; kh < 3; ++kh) {
        int y = h + kh - 1;
        if ((unsigned)y >= H_) continue;
#pragma unroll
        for (int kw = 0; kw < 3; ++kw) {
            int xx = w + kw - 1;
            if ((unsigned)xx >= W_) continue;
            acc = fmaf(t[(size_t)(n * HW_ + y * W_ + xx) * C_ + c], dww[(kh * 3 + kw) * C_ + c], acc);
        }
    }
    float2 r  = block_sum2(acc, acc * acc, sm);
    float mu  = r.x * (1.f / C_);
    float var = fmaxf(r.y * (1.f / C_) - mu * mu, 0.f);
    float rs  = rsqrtf(var + 1e-6f);
    float val = (acc - mu) * rs * lg[c] + lb[c];
    x1_bf[(size_t)pix * C_ + c] = f2bf(gelu_exact(val));
}

// ---------------- offset+mask via MFMA (N=256: 144 off | 72 msk | 40 pad) + softmax ----------------
__global__ __launch_bounds__(256) void k_offmask_mfma(const unsigned short* __restrict__ x1_bf,
                                                      const unsigned short* __restrict__ omT,
                                                      const float* __restrict__ omb,
                                                      float* __restrict__ offo, float* __restrict__ msko) {
    __shared__ float som[32][225];
    int wave = threadIdx.x >> 6, lane = threadIdx.x & 63;
    int r = lane & 15, kq = lane >> 4;
    int p0 = blockIdx.x * 32, co0 = wave * 64;
    f32x4 acc[2][4] = {};
#pragma unroll 1
    for (int ks = 0; ks < 8; ++ks) {
        bf16x8 a0 = *(const bf16x8*)(x1_bf + (size_t)(p0 + r) * C_ + ks * 32 + kq * 8);
        bf16x8 a1 = *(const bf16x8*)(x1_bf + (size_t)(p0 + 16 + r) * C_ + ks * 32 + kq * 8);
        const unsigned short* bp = omT + (size_t)(co0 + r) * C_ + ks * 32 + kq * 8;
#pragma unroll
        for (int ni = 0; ni < 4; ++ni) {
            bf16x8 b = *(const bf16x8*)(bp + (size_t)ni * 16 * C_);
            acc[0][ni] = __builtin_amdgcn_mfma_f32_16x16x32_bf16(a0, b, acc[0][ni], 0, 0, 0);
            acc[1][ni] = __builtin_amdgcn_mfma_f32_16x16x32_bf16(a1, b, acc[1][ni], 0, 0, 0);
        }
    }
#pragma unroll
    for (int ni = 0; ni < 4; ++ni) {
        int col = co0 + ni * 16 + r;
        if (col < 216) {
            float bb = omb[col];
#pragma unroll
            for (int mi = 0; mi < 2; ++mi)
#pragma unroll
                for (int reg = 0; reg < 4; ++reg)
                    som[mi * 16 + kq * 4 + reg][col] = acc[mi][ni][reg] + bb;
        }
    }
    __syncthreads();
    int tid = threadIdx.x;
#pragma unroll
    for (int i = 0; i < 18; ++i) {
        int j = i * 256 + tid;          // 32*144 = 4608
        int px = j / 144, col = j - px * 144;
        offo[(size_t)(p0 + px) * 144 + col] = som[px][col];
    }
    int px = tid >> 3, g = tid & 7;
    float mx = -1e30f;
#pragma unroll
    for (int p = 0; p < 9; ++p) mx = fmaxf(mx, som[px][144 + g * 9 + p]);
    float e[9], s = 0.f;
#pragma unroll
    for (int p = 0; p < 9; ++p) { e[p] = expf(som[px][144 + g * 9 + p] - mx); s += e[p]; }
    float inv = 1.f / s;
#pragma unroll
    for (int p = 0; p < 9; ++p) msko[(size_t)(p0 + px) * 72 + g * 9 + p] = e[p] * inv;
}

// ---------------- DCNv3 deformable sampling core -> core_bf ----------------
__global__ __launch_bounds__(256) void k_core(const float* __restrict__ xp,
                                              const float* __restrict__ offo, const float* __restrict__ msko,
                                              unsigned short* __restrict__ core_bf) {
    int pix = blockIdx.x;
    int n = pix / HW_, hw = pix - n * HW_;
    int h = hw / W_,  w = hw - h * W_;
    int g  = threadIdx.x >> 5;
    int cc = threadIdx.x & 31;
    const float* op = offo + (size_t)pix * 144 + g * 18;
    const float* mp = msko + (size_t)pix * 72 + g * 9;
    const float* xg = xp + (size_t)n * HW_ * C_ + g * GC_ + cc;
    float acc = 0.f;
#pragma unroll
    for (int p = 0; p < 9; ++p) {
        float gx = (float)(w + (p / 3)) + op[p * 2];
        float gy = (float)(h + (p % 3)) + op[p * 2 + 1];
        float fx = floorf(gx), fy = floorf(gy);
        float wx = gx - fx,   wy = gy - fy;
        int ix = (int)fx - 1, iy = (int)fy - 1;
        float v00 = 0.f, v10 = 0.f, v01 = 0.f, v11 = 0.f;
        bool x0ok = (unsigned)ix < W_, x1ok = (unsigned)(ix + 1) < W_;
        bool y0ok = (unsigned)iy < H_, y1ok = (unsigned)(iy + 1) < H_;
        if (y0ok) {
            const float* rr = xg + (size_t)(iy * W_) * C_;
            if (x0ok) v00 = rr[(size_t)ix * C_];
            if (x1ok) v10 = rr[(size_t)(ix + 1) * C_];
        }
        if (y1ok) {
            const float* rr = xg + (size_t)((iy + 1) * W_) * C_;
            if (x0ok) v01 = rr[(size_t)ix * C_];
            if (x1ok) v11 = rr[(size_t)(ix + 1) * C_];
        }
        float sval = (v00 * (1.f - wx) + v10 * wx) * (1.f - wy)
                   + (v01 * (1.f - wx) + v11 * wx) * wy;
        acc = fmaf(mp[p], sval, acc);
    }
    core_bf[(size_t)pix * C_ + threadIdx.x] = f2bf(acc);
}

// ---------------- output proj MFMA + LN(1e-5) + gamma1 residual -> t, t_bf ----------------
__global__ __launch_bounds__(256) void k_outproj_mfma(const unsigned short* __restrict__ core_bf,
                                                      const unsigned short* __restrict__ outpwT,
                                                      const float* __restrict__ bo,
                                                      const float* __restrict__ g1, const float* __restrict__ lg,
                                                      const float* __restrict__ lb,
                                                      float* __restrict__ t, unsigned short* __restrict__ t_bf) {
    __shared__ float sd[32][260];
    int wave = threadIdx.x >> 6, lane = threadIdx.x & 63;
    int r = lane & 15, kq = lane >> 4;
    int p0 = blockIdx.x * 32, co0 = wave * 64;
    f32x4 acc[2][4] = {};
#pragma unroll 1
    for (int ks = 0; ks < 8; ++ks) {
        bf16x8 a0 = *(const bf16x8*)(core_bf + (size_t)(p0 + r) * C_ + ks * 32 + kq * 8);
        bf16x8 a1 = *(const bf16x8*)(core_bf + (size_t)(p0 + 16 + r) * C_ + ks * 32 + kq * 8);
        const unsigned short* bp = outpwT + (size_t)(co0 + r) * C_ + ks * 32 + kq * 8;
#pragma unroll
        for (int ni = 0; ni < 4; ++ni) {
            bf16x8 b = *(const bf16x8*)(bp + (size_t)ni * 16 * C_);
            acc[0][ni] = __builtin_amdgcn_mfma_f32_16x16x32_bf16(a0, b, acc[0][ni], 0, 0, 0);
            acc[1][ni] = __builtin_amdgcn_mfma_f32_16x16x32_bf16(a1, b, acc[1][ni], 0, 0, 0);
        }
    }
#pragma unroll
    for (int ni = 0; ni < 4; ++ni) {
        int col = co0 + ni * 16 + r;
        float bb = bo[col];
#pragma unroll
        for (int mi = 0; mi < 2; ++mi)
#pragma unroll
            for (int reg = 0; reg < 4; ++reg)
                sd[mi * 16 + kq * 4 + reg][col] = acc[mi][ni][reg] + bb;
    }
    __syncthreads();
    int px = threadIdx.x >> 3, sub = threadIdx.x & 7;
    float s1 = 0.f, s2 = 0.f;
#pragma unroll
    for (int i = 0; i < 8; ++i) {
        float4 vv = *(const float4*)&sd[px][sub * 32 + i * 4];
        s1 += vv.x + vv.y + vv.z + vv.w;
        s2 += vv.x * vv.x + vv.y * vv.y + vv.z * vv.z + vv.w * vv.w;
    }
#pragma unroll
    for (int off = 1; off < 8; off <<= 1) { s1 += __shfl_xor(s1, off, 64); s2 += __shfl_xor(s2, off, 64); }
    float mu  = s1 * (1.f / C_);
    float var = fmaxf(s2 * (1.f / C_) - mu * mu, 0.f);
    float rs  = rsqrtf(var + 1e-5f);
#pragma unroll
    for (int i = 0; i < 32; ++i) {
        int col = sub * 32 + i;
        size_t idx = (size_t)(p0 + px) * C_ + col;
        float tn = t[idx] + g1[col] * ((sd[px][col] - mu) * rs * lg[col] + lb[col]);
        t[idx] = tn;
        t_bf[idx] = f2bf(tn);
    }
}

// ---------------- fc1 GEMM (M=NHW,N=1024,K=256) + GELU -> h_bf ----------------
// 128x128 tile, 4 waves (2x2), BK=64; async global_load_lds into fragment-major chunks;
// output staged via padded LDS for coalesced 16B stores.
__global__ __launch_bounds__(256) void k_fc1_mfma(const unsigned short* __restrict__ t_bf,
                                                  const unsigned short* __restrict__ fc1wT,
                                                  const float* __restrict__ fc1b,
                                                  unsigned short* __restrict__ h_bf) {
    __shared__ __align__(16) unsigned char smem[34816];   // staging 32KB; out 128*136*2=34816B
    unsigned short* sm16 = (unsigned short*)smem;
    bf16x8* sA = (bf16x8*)smem;                 // 16 chunks * 64
    bf16x8* sB = (bf16x8*)(smem + 16384);       // 16 chunks * 64
    int tid = threadIdx.x;
    int wave = tid >> 6, lane = tid & 63;
    int r = lane & 15, kq = lane >> 4;
    int mt = blockIdx.x >> 3, nt = blockIdx.x & 7;
    int m0 = mt * 128, n0 = nt * 128;
    int wm = wave & 1, wn = wave >> 1;

    f32x4 acc[4][4] = {};
#pragma unroll 1
    for (int kt = 0; kt < 4; ++kt) {
        int k0 = kt * 64;
        if (kt) __syncthreads();               // previous tile's reads done
#pragma unroll
        for (int i = 0; i < 4; ++i) {          // A chunks q = wave*4+i
            int q = wave * 4 + i;
            int row = m0 + (q >> 1) * 16 + r;
            int cc  = (q & 1) * 4 + kq;
            GLOAD_LDS16(t_bf + (size_t)row * C_ + k0 + cc * 8, sm16 + q * 512);
        }
#pragma unroll
        for (int i = 0; i < 4; ++i) {          // B chunks q = wave*4+i
            int q = wave * 4 + i;
            int nrow = n0 + (q >> 1) * 16 + r;
            int cc   = (q & 1) * 4 + kq;
            GLOAD_LDS16(fc1wT + (size_t)nrow * C_ + k0 + cc * 8, sm16 + 8192 + q * 512);
        }
        __syncthreads();                       // drains vmcnt before barrier
#pragma unroll
        for (int ks = 0; ks < 2; ++ks) {
            bf16x8 af[4], bfr[4];
#pragma unroll
            for (int mi = 0; mi < 4; ++mi) af[mi]  = sA[((wm * 4 + mi) * 2 + ks) * 64 + lane];
#pragma unroll
            for (int ni = 0; ni < 4; ++ni) bfr[ni] = sB[((wn * 4 + ni) * 2 + ks) * 64 + lane];
#pragma unroll
            for (int mi = 0; mi < 4; ++mi)
#pragma unroll
                for (int ni = 0; ni < 4; ++ni)
                    acc[mi][ni] = __builtin_amdgcn_mfma_f32_16x16x32_bf16(af[mi], bfr[ni], acc[mi][ni], 0, 0, 0);
        }
    }
    __syncthreads();                           // all ds_reads done before out-staging overwrites
#pragma unroll
    for (int ni = 0; ni < 4; ++ni) {
        int col = (wn * 4 + ni) * 16 + r;
        float bb = fc1b[n0 + col];
#pragma unroll
        for (int mi = 0; mi < 4; ++mi)
#pragma unroll
            for (int reg = 0; reg < 4; ++reg) {
                int row = (wm * 4 + mi) * 16 + kq * 4 + reg;
                sm16[row * 136 + col] = f2bf(gelu_exact(acc[mi][ni][reg] + bb));
            }
    }
    __syncthreads();
    int trow = tid >> 1, thalf = tid & 1;
    const unsigned short* src = sm16 + trow * 136 + thalf * 64;
    unsigned short* dst = h_bf + (size_t)(m0 + trow) * HID_ + n0 + thalf * 64;
#pragma unroll
    for (int j = 0; j < 8; ++j)
        *(bf16x8*)(dst + j * 8) = *(const bf16x8*)(src + j * 8);
}

// ---------------- fc2 GEMM (M=NHW,N=256,K=1024) + LN(1e-5) + gamma2 residual into t ----------------
// 64x256 tile, 4 waves split M (16 rows each, full 256 cols -> in-wave LN), BK=64, async staging.
__global__ __launch_bounds__(256) void k_fc2ln_mfma(const unsigned short* __restrict__ h_bf,
                                                    const unsigned short* __restrict__ fc2wT,
                                                    const float* __restrict__ fc2b,
                                                    const float* __restrict__ g2, const float* __restrict__ lg,
                                                    const float* __restrict__ lb, float* __restrict__ t) {
    __shared__ __align__(16) unsigned char smem[40960];   // A 8KB + B 32KB
    unsigned short* sm16 = (unsigned short*)smem;
    bf16x8* sA = (bf16x8*)smem;                 // 8 chunks * 64
    bf16x8* sB = (bf16x8*)(smem + 8192);        // 32 chunks * 64
    int tid = threadIdx.x;
    int wave = tid >> 6, lane = tid & 63;
    int r = lane & 15, kq = lane >> 4;
    int m0 = blockIdx.x * 64;

    f32x4 acc[16] = {};
#pragma unroll 1
    for (int kt = 0; kt < 16; ++kt) {
        int k0 = kt * 64;
        if (kt) __syncthreads();
#pragma unroll
        for (int i = 0; i < 2; ++i) {          // A chunks q = wave*2+i  (mfrag = q>>1 = wave)
            int q = wave * 2 + i;
            int row = m0 + (q >> 1) * 16 + r;
            int cc  = (q & 1) * 4 + kq;
            GLOAD_LDS16(h_bf + (size_t)row * HID_ + k0 + cc * 8, sm16 + q * 512);
        }
#pragma unroll
        for (int i = 0; i < 8; ++i) {          // B chunks q = wave*8+i
            int q = wave * 8 + i;
            int nrow = (q >> 1) * 16 + r;
            int cc   = (q & 1) * 4 + kq;
            GLOAD_LDS16(fc2wT + (size_t)nrow * HID_ + k0 + cc * 8, sm16 + 4096 + q * 512);
        }
        __syncthreads();
#pragma unroll
        for (int ks = 0; ks < 2; ++ks) {
            bf16x8 a = sA[(wave * 2 + ks) * 64 + lane];
#pragma unroll
            for (int ni = 0; ni < 16; ++ni) {
                bf16x8 b = sB[(ni * 2 + ks) * 64 + lane];
                acc[ni] = __builtin_amdgcn_mfma_f32_16x16x32_bf16(a, b, acc[ni], 0, 0, 0);
            }
        }
    }
    // epilogue: bias, per-row LN over 256 cols (in-wave), gamma2 residual into t
    float bb[16], g2v[16], lgv[16], lbv[16];
#pragma unroll
    for (int ni = 0; ni < 16; ++ni) {
        int col = ni * 16 + r;
        bb[ni] = fc2b[col]; g2v[ni] = g2[col]; lgv[ni] = lg[col]; lbv[ni] = lb[col];
    }
#pragma unroll
    for (int ni = 0; ni < 16; ++ni)
#pragma unroll
        for (int reg = 0; reg < 4; ++reg) acc[ni][reg] += bb[ni];
#pragma unroll
    for (int reg = 0; reg < 4; ++reg) {
        float s1 = 0.f, s2 = 0.f;
#pragma unroll
        for (int ni = 0; ni < 16; ++ni) { float vv = acc[ni][reg]; s1 += vv; s2 += vv * vv; }
#pragma unroll
        for (int off = 1; off < 16; off <<= 1) { s1 += __shfl_xor(s1, off, 64); s2 += __shfl_xor(s2, off, 64); }
        float mu  = s1 * (1.f / C_);
        float var = fmaxf(s2 * (1.f / C_) - mu * mu, 0.f);
        float rs  = rsqrtf(var + 1e-5f);
        int row = m0 + wave * 16 + kq * 4 + reg;
        float* tr = t + (size_t)row * C_;
#pragma unroll
        for (int ni = 0; ni < 16; ++ni) {
            int col = ni * 16 + r;
            tr[col] += g2v[ni] * ((acc[ni][reg] - mu) * rs * lgv[ni] + lbv[ni]);
        }
    }
}

// ---------------- BN2 + input residual + ReLU -> out (NCHW) ----------------
__global__ __launch_bounds__(256) void k_final(const float* __restrict__ t, const float* __restrict__ x,
                                               const float* __restrict__ g, const float* __restrict__ b,
                                               const float* __restrict__ m, const float* __restrict__ v,
                                               float* __restrict__ out) {
    int i  = blockIdx.x * 256 + threadIdx.x;
    int hw = i % HW_;
    int r  = i / HW_;
    int c  = r & 255;
    int n  = r >> 8;
    float tv  = t[(size_t)(n * HW_ + hw) * C_ + c];
    float s   = rsqrtf(v[c] + 1e-5f);
    float val = (tv - m[c]) * (g[c] * s) + b[c] + x[i];
    out[i] = fmaxf(val, 0.f);
}

extern "C" void kernel_launch(void* const* d_in, const int* in_sizes, int n_in,
                              void* d_out, int out_size, void* d_ws, size_t ws_size,
                              hipStream_t stream) {
    const float* x      = (const float*)d_in[0];
    const float* conv1w = (const float*)d_in[1];
    const float* bn1g   = (const float*)d_in[2];
    const float* bn1b   = (const float*)d_in[3];
    const float* bn1m   = (const float*)d_in[4];
    const float* bn1v   = (const float*)d_in[5];
    const float* ln1g   = (const float*)d_in[6];
    const float* ln1b   = (const float*)d_in[7];
    const float* dww    = (const float*)d_in[8];
    const float* dwb    = (const float*)d_in[9];
    const float* dwlng  = (const float*)d_in[10];
    const float* dwlnb  = (const float*)d_in[11];
    const float* offw   = (const float*)d_in[12];
    const float* offb   = (const float*)d_in[13];
    const float* mskw   = (const float*)d_in[14];
    const float* mskb   = (const float*)d_in[15];
    const float* inpw   = (const float*)d_in[16];
    const float* inpb   = (const float*)d_in[17];
    const float* outpw  = (const float*)d_in[18];
    const float* outpb  = (const float*)d_in[19];
    const float* gamma1 = (const float*)d_in[20];
    const float* ln2g   = (const float*)d_in[21];
    const float* ln2b   = (const float*)d_in[22];
    const float* fc1w   = (const float*)d_in[23];
    const float* fc1b   = (const float*)d_in[24];
    const float* fc2w   = (const float*)d_in[25];
    const float* fc2b   = (const float*)d_in[26];
    const float* gamma2 = (const float*)d_in[27];
    const float* bn2g   = (const float*)d_in[28];
    const float* bn2b   = (const float*)d_in[29];
    const float* bn2m   = (const float*)d_in[30];
    const float* bn2v   = (const float*)d_in[31];
    float* out = (float*)d_out;

    // ---- workspace layout (dead-by-MLP region first, aliased by h_bf) ----
    float* ws    = (float*)d_ws;
    float* xproj = ws;                                    // [NHW][256] f32   (dead after core)
    float* offo  = xproj + (size_t)NHW_ * C_;             // [NHW][144] f32   (dead after core)
    float* msko  = offo  + (size_t)NHW_ * 144;            // [NHW][72]  f32   (dead after core)
    unsigned short* x1_bf = (unsigned short*)(msko + (size_t)NHW_ * 72);   // [NHW][256] (dead after offmask)
    unsigned short* scr   = x1_bf + (size_t)NHW_ * C_;    // xpad / core_bf alias
    float* t     = (float*)(scr + (size_t)N_ * XP_H * XP_W * C_);          // [NHW][256] f32
    float* omb   = t + (size_t)NHW_ * C_;                 // [256] f32
    unsigned short* t_bf  = (unsigned short*)(omb + 256); // [NHW][256]
    unsigned short* wTT   = t_bf  + (size_t)NHW_ * C_;    // [9][256][256]
    unsigned short* inpwT = wTT   + (size_t)9 * C_ * C_;  // [256][256]
    unsigned short* outpwT= inpwT + (size_t)C_ * C_;
    unsigned short* fc1wT = outpwT+ (size_t)C_ * C_;      // [1024][256]
    unsigned short* fc2wT = fc1wT + (size_t)HID_ * C_;    // [256][1024]
    unsigned short* omT   = fc2wT + (size_t)C_ * HID_;    // [256][256]
    unsigned short* xpad    = scr;
    unsigned short* core_bf = scr;
    unsigned short* h_bf    = (unsigned short*)xproj;     // [NHW][1024] aliases xproj..x1_bf (51.4MB < 60.2MB)

    hipMemsetAsync(xpad, 0, (size_t)N_ * XP_H * XP_W * C_ * sizeof(unsigned short), stream);
    k_prep_xpad<<<N_ * H_, 256, 0, stream>>>(x, xpad);
    k_prep_wTT <<<2304,    256, 0, stream>>>(conv1w, wTT);
    k_prep_sqT <<<256,     256, 0, stream>>>(inpw, inpwT);
    k_prep_sqT <<<256,     256, 0, stream>>>(outpw, outpwT);
    k_prep_fc1T<<<1024,    256, 0, stream>>>(fc1w, fc1wT);
    k_prep_fc2T<<<256,     256, 0, stream>>>(fc2w, fc2wT);
    k_prep_om  <<<256,     256, 0, stream>>>(offw, offb, mskw, mskb, omT, omb);

    k_conv1_mfma  <<<(NHW_ / 64) * 2, 256, 0, stream>>>(xpad, wTT, bn1g, bn1b, bn1m, bn1v, t, t_bf);
    k_inproj_mfma <<<NHW_ / 32, 256, 0, stream>>>(t_bf, inpwT, inpb, xproj);
    k_dw          <<<NHW_,      256, 0, stream>>>(t, dww, dwb, dwlng, dwlnb, x1_bf);
    k_offmask_mfma<<<NHW_ / 32, 256, 0, stream>>>(x1_bf, omT, omb, offo, msko);
    k_core        <<<NHW_,      256, 0, stream>>>(xproj, offo, msko, core_bf);
    k_outproj_mfma<<<NHW_ / 32, 256, 0, stream>>>(core_bf, outpwT, outpb, gamma1, ln1g, ln1b, t, t_bf);
    k_fc1_mfma    <<<(NHW_ / 128) * 8, 256, 0, stream>>>(t_bf, fc1wT, fc1b, h_bf);
    k_fc2ln_mfma  <<<NHW_ / 64, 256, 0, stream>>>(h_bf, fc2wT, fc2b, gamma2, ln2g, ln2b, t);
    k_final       <<<NHW_,      256, 0, stream>>>(t, x, bn2g, bn2b, bn2m, bn2v, out);
}

// Round 8
// 646.958 us; speedup vs baseline: 1.3853x; 1.0167x over previous
//
#include <hip/hip_runtime.h>
#include <cmath>

#define N_   8
#define H_   56
#define W_   56
#define C_   256
#define HW_  3136
#define NHW_ 25088
#define G_   8
#define GC_  32
#define P_   9
#define HID_ 1024
#define XP_H 58
#define XP_W 58

typedef __attribute__((ext_vector_type(8))) short bf16x8;
typedef __attribute__((ext_vector_type(4))) float f32x4;

#define GLOAD_LDS16(g, l) __builtin_amdgcn_global_load_lds( \
    (const __attribute__((address_space(1))) void*)(g), \
    (__attribute__((address_space(3))) void*)(l), 16, 0, 0)

__device__ __forceinline__ unsigned short f2bf(float f) {
    unsigned u = __float_as_uint(f);
    u += 0x7FFF + ((u >> 16) & 1);   // round-to-nearest-even
    return (unsigned short)(u >> 16);
}

__device__ __forceinline__ float gelu_exact(float v) {
    return 0.5f * v * (1.f + erff(v * 0.70710678118654752f));
}

// ---------------- block-wide sum of (a,b) over 256 threads ----------------
__device__ __forceinline__ float2 block_sum2(float a, float b, float* sm) {
    int lane = threadIdx.x & 63;
    int wid  = threadIdx.x >> 6;
#pragma unroll
    for (int off = 32; off > 0; off >>= 1) {
        a += __shfl_down(a, off, 64);
        b += __shfl_down(b, off, 64);
    }
    if (lane == 0) { sm[wid] = a; sm[wid + 4] = b; }
    __syncthreads();
    float ra = sm[0] + sm[1] + sm[2] + sm[3];
    float rb = sm[4] + sm[5] + sm[6] + sm[7];
    __syncthreads();
    return make_float2(ra, rb);
}

// ---------------- x (NCHW fp32) -> xpad (N,58,58,256 bf16), border pre-zeroed ----------------
__global__ __launch_bounds__(256) void k_prep_xpad(const float* __restrict__ x, unsigned short* __restrict__ xpad) {
    int nh = blockIdx.x;                   // N_*H_ = 448
    int n = nh / H_, h = nh - n * H_;
    int c = threadIdx.x;
    const float* xr = x + ((size_t)(n * C_ + c)) * HW_ + h * W_;
    unsigned short* orow = xpad + ((size_t)((n * XP_H + h + 1) * XP_W + 1)) * C_ + c;
    for (int w = 0; w < W_; ++w) orow[(size_t)w * C_] = f2bf(xr[w]);
}

// ---------------- conv1 weights [co][ci][3][3] -> wTT [kk][co][ci] bf16 ----------------
__global__ __launch_bounds__(256) void k_prep_wTT(const float* __restrict__ w, unsigned short* __restrict__ wTT) {
    int i  = blockIdx.x * 256 + threadIdx.x;   // 9*256*256
    int ci = i & 255;
    int r  = i >> 8;
    int co = r & 255;
    int kk = r >> 8;
    wTT[i] = f2bf(w[(co * 256 + ci) * 9 + kk]);
}

// ---------------- square 256x256 weight -> W^T bf16 [n][k] ----------------
__global__ __launch_bounds__(256) void k_prep_sqT(const float* __restrict__ src, unsigned short* __restrict__ dst) {
    int n = blockIdx.x, k = threadIdx.x;
    dst[n * C_ + k] = f2bf(src[k * C_ + n]);
}

// ---------------- fc1 [256][1024] -> [1024][256] bf16 ----------------
__global__ __launch_bounds__(256) void k_prep_fc1T(const float* __restrict__ src, unsigned short* __restrict__ dst) {
    int n = blockIdx.x, k = threadIdx.x;
    dst[(size_t)n * C_ + k] = f2bf(src[(size_t)k * HID_ + n]);
}

// ---------------- fc2 [1024][256] -> [256][1024] bf16 ----------------
__global__ __launch_bounds__(256) void k_prep_fc2T(const float* __restrict__ src, unsigned short* __restrict__ dst) {
    int n = blockIdx.x, k0 = threadIdx.x;
#pragma unroll
    for (int q = 0; q < 4; ++q) {
        int k = q * 256 + k0;
        dst[(size_t)n * HID_ + k] = f2bf(src[(size_t)k * C_ + n]);
    }
}

// ---------------- offw[256][144] + mskw[256][72] -> omT [256][256] bf16 (+ omb) ----------------
__global__ __launch_bounds__(256) void k_prep_om(const float* __restrict__ offw, const float* __restrict__ offb,
                                                 const float* __restrict__ mskw, const float* __restrict__ mskb,
                                                 unsigned short* __restrict__ omT, float* __restrict__ omb) {
    int n = blockIdx.x, k = threadIdx.x;
    float v = 0.f;
    if (n < 144)      v = offw[k * 144 + n];
    else if (n < 216) v = mskw[k * 72 + (n - 144)];
    omT[n * C_ + k] = f2bf(v);
    if (k == 0) omb[n] = (n < 144) ? offb[n] : (n < 216 ? mskb[n - 144] : 0.f);
}

// ---------------- conv1 implicit GEMM: 64x128 tile, BK=64, double-buffered async staging ----------------
// K = 9 taps x 256; kt = tap*4 + ktk. 2-phase pipeline: STAGE(kt+1) -> vmcnt(6) -> barrier -> MFMA(kt).
__global__ __launch_bounds__(256) void k_conv1_mfma(const unsigned short* __restrict__ xpad,
                                                    const unsigned short* __restrict__ wTT,
                                                    const float* __restrict__ g, const float* __restrict__ b,
                                                    const float* __restrict__ m, const float* __restrict__ v,
                                                    float* __restrict__ t, unsigned short* __restrict__ t_bf) {
    __shared__ __align__(16) unsigned char smem[49152];   // 2 x (A 8KB + B 16KB)
    unsigned short* sm16 = (unsigned short*)smem;
    int tid = threadIdx.x;
    int wave = tid >> 6, lane = tid & 63;
    int r = lane & 15, kq = lane >> 4;
    int mt = blockIdx.x >> 1, nt = blockIdx.x & 1;
    int m0 = mt * 64, n0 = nt * 128;
    int wm = wave & 1, wn = wave >> 1;

    // per-lane A-row base: row = m0 + wave*16 + r
    int pix = m0 + wave * 16 + r;
    int n = pix / HW_, hw = pix - n * HW_;
    int h = hw / W_, w = hw - h * W_;
    size_t abase = ((size_t)((n * XP_H + h) * XP_W + w)) * C_;

    f32x4 acc[2][4] = {};

    auto stage = [&](int kt, int buf) {
        int tap = kt >> 2, ktk = kt & 3;
        int kh = tap / 3, kw = tap - kh * 3;
        int k0 = ktk * 64;
        unsigned short* dstA = sm16 + buf * 12288;
        unsigned short* dstB = dstA + 4096;
        const unsigned short* ap = xpad + abase + (size_t)(kh * XP_W + kw) * C_ + k0;
#pragma unroll
        for (int i = 0; i < 2; ++i)
            GLOAD_LDS16(ap + (i * 4 + kq) * 8, dstA + (wave * 2 + i) * 512);
#pragma unroll
        for (int i = 0; i < 4; ++i) {
            int q = wave * 4 + i;
            int nrow = n0 + (q >> 1) * 16 + r;
            int cc   = (q & 1) * 4 + kq;
            GLOAD_LDS16(wTT + ((size_t)(tap * C_) + nrow) * C_ + k0 + cc * 8, dstB + q * 512);
        }
    };

    stage(0, 0);
    int cur = 0;
#pragma unroll 1
    for (int kt = 0; kt < 36; ++kt) {
        if (kt < 35) {
            stage(kt + 1, cur ^ 1);
            asm volatile("s_waitcnt vmcnt(6)" ::: "memory");
        } else {
            asm volatile("s_waitcnt vmcnt(0)" ::: "memory");
        }
        __builtin_amdgcn_s_barrier();
        bf16x8* sA = (bf16x8*)(sm16 + cur * 12288);
        bf16x8* sB = sA + 512;
#pragma unroll
        for (int ks = 0; ks < 2; ++ks) {
            bf16x8 af[2], bfr[4];
#pragma unroll
            for (int mi = 0; mi < 2; ++mi) af[mi]  = sA[((wm * 2 + mi) * 2 + ks) * 64 + lane];
#pragma unroll
            for (int ni = 0; ni < 4; ++ni) bfr[ni] = sB[((wn * 4 + ni) * 2 + ks) * 64 + lane];
#pragma unroll
            for (int mi = 0; mi < 2; ++mi)
#pragma unroll
                for (int ni = 0; ni < 4; ++ni)
                    acc[mi][ni] = __builtin_amdgcn_mfma_f32_16x16x32_bf16(af[mi], bfr[ni], acc[mi][ni], 0, 0, 0);
        }
        __builtin_amdgcn_s_barrier();
        cur ^= 1;
    }

#pragma unroll
    for (int ni = 0; ni < 4; ++ni) {
        int co = n0 + (wn * 4 + ni) * 16 + r;
        float sc = g[co] * rsqrtf(v[co] + 1e-5f);
        float sh = b[co] - m[co] * sc;
#pragma unroll
        for (int mi = 0; mi < 2; ++mi) {
#pragma unroll
            for (int reg = 0; reg < 4; ++reg) {
                int po = m0 + (wm * 2 + mi) * 16 + kq * 4 + reg;
                float val = fmaxf(acc[mi][ni][reg] * sc + sh, 0.f);
                size_t idx = (size_t)po * C_ + co;
                t[idx] = val;
                t_bf[idx] = f2bf(val);
            }
        }
    }
}

// ---------------- input proj: 64x256 staged-dbuf GEMM (K=256) -> xproj f32 ----------------
__global__ __launch_bounds__(256) void k_inproj_mfma(const unsigned short* __restrict__ t_bf,
                                                     const unsigned short* __restrict__ inpwT,
                                                     const float* __restrict__ bias,
                                                     float* __restrict__ xproj) {
    __shared__ __align__(16) unsigned char smem[81920];   // 2 x (A 8KB + B 32KB)
    unsigned short* sm16 = (unsigned short*)smem;
    int tid = threadIdx.x;
    int wave = tid >> 6, lane = tid & 63;
    int r = lane & 15, kq = lane >> 4;
    int m0 = blockIdx.x * 64;

    f32x4 acc[16] = {};

    auto stage = [&](int kt, int buf) {
        int k0 = kt * 64;
        unsigned short* dstA = sm16 + buf * 20480;
        unsigned short* dstB = dstA + 4096;
#pragma unroll
        for (int i = 0; i < 2; ++i) {
            int q = wave * 2 + i;
            int row = m0 + wave * 16 + r;
            GLOAD_LDS16(t_bf + (size_t)row * C_ + k0 + (i * 4 + kq) * 8, dstA + q * 512);
        }
#pragma unroll
        for (int i = 0; i < 8; ++i) {
            int q = wave * 8 + i;
            int nrow = (q >> 1) * 16 + r;
            int cc   = (q & 1) * 4 + kq;
            GLOAD_LDS16(inpwT + (size_t)nrow * C_ + k0 + cc * 8, dstB + q * 512);
        }
    };

    stage(0, 0);
    int cur = 0;
#pragma unroll 1
    for (int kt = 0; kt < 4; ++kt) {
        if (kt < 3) {
            stage(kt + 1, cur ^ 1);
            asm volatile("s_waitcnt vmcnt(10)" ::: "memory");
        } else {
            asm volatile("s_waitcnt vmcnt(0)" ::: "memory");
        }
        __builtin_amdgcn_s_barrier();
        bf16x8* sA = (bf16x8*)(sm16 + cur * 20480);
        bf16x8* sB = sA + 512;
#pragma unroll
        for (int ks = 0; ks < 2; ++ks) {
            bf16x8 a = sA[(wave * 2 + ks) * 64 + lane];
#pragma unroll
            for (int ni = 0; ni < 16; ++ni) {
                bf16x8 b = sB[(ni * 2 + ks) * 64 + lane];
                acc[ni] = __builtin_amdgcn_mfma_f32_16x16x32_bf16(a, b, acc[ni], 0, 0, 0);
            }
        }
        __builtin_amdgcn_s_barrier();
        cur ^= 1;
    }

#pragma unroll
    for (int ni = 0; ni < 16; ++ni) {
        int col = ni * 16 + r;
        float bb = bias[col];
#pragma unroll
        for (int reg = 0; reg < 4; ++reg) {
            int row = m0 + wave * 16 + kq * 4 + reg;
            xproj[(size_t)row * C_ + col] = acc[ni][reg] + bb;
        }
    }
}

// ---------------- depthwise 3x3 + LN(1e-6) + exact GELU -> x1_bf ----------------
__global__ __launch_bounds__(256) void k_dw(const float* __restrict__ t, const float* __restrict__ dww,
                                            const float* __restrict__ dwb, const float* __restrict__ lg,
                                            const float* __restrict__ lb, unsigned short* __restrict__ x1_bf) {
    __shared__ float sm[8];
    int pix = blockIdx.x;
    int n = pix / HW_, hw = pix - n * HW_;
    int h = hw / W_,  w = hw - h * W_;
    int c = threadIdx.x;
    float acc = dwb[c];
#pragma unroll
    for (int kh = 0; kh < 3; ++kh) {
        int y = h + kh - 1;
        if ((unsigned)y >= H_) continue;
#pragma unroll
        for (int kw = 0; kw < 3; ++kw) {
            int xx = w + kw - 1;
            if ((unsigned)xx >= W_) continue;
            acc = fmaf(t[(size_t)(n * HW_ + y * W_ + xx) * C_ + c], dww[(kh * 3 + kw) * C_ + c], acc);
        }
    }
    float2 r  = block_sum2(acc, acc * acc, sm);
    float mu  = r.x * (1.f / C_);
    float var = fmaxf(r.y * (1.f / C_) - mu * mu, 0.f);
    float rs  = rsqrtf(var + 1e-6f);
    float val = (acc - mu) * rs * lg[c] + lb[c];
    x1_bf[(size_t)pix * C_ + c] = f2bf(gelu_exact(val));
}

// ---------------- offset+mask via MFMA (N=256: 144 off | 72 msk | 40 pad) + softmax ----------------
__global__ __launch_bounds__(256) void k_offmask_mfma(const unsigned short* __restrict__ x1_bf,
                                                      const unsigned short* __restrict__ omT,
                                                      const float* __restrict__ omb,
                                                      float* __restrict__ offo, float* __restrict__ msko) {
    __shared__ float som[32][225];
    int wave = threadIdx.x >> 6, lane = threadIdx.x & 63;
    int r = lane & 15, kq = lane >> 4;
    int p0 = blockIdx.x * 32, co0 = wave * 64;
    f32x4 acc[2][4] = {};
#pragma unroll 1
    for (int ks = 0; ks < 8; ++ks) {
        bf16x8 a0 = *(const bf16x8*)(x1_bf + (size_t)(p0 + r) * C_ + ks * 32 + kq * 8);
        bf16x8 a1 = *(const bf16x8*)(x1_bf + (size_t)(p0 + 16 + r) * C_ + ks * 32 + kq * 8);
        const unsigned short* bp = omT + (size_t)(co0 + r) * C_ + ks * 32 + kq * 8;
#pragma unroll
        for (int ni = 0; ni < 4; ++ni) {
            bf16x8 b = *(const bf16x8*)(bp + (size_t)ni * 16 * C_);
            acc[0][ni] = __builtin_amdgcn_mfma_f32_16x16x32_bf16(a0, b, acc[0][ni], 0, 0, 0);
            acc[1][ni] = __builtin_amdgcn_mfma_f32_16x16x32_bf16(a1, b, acc[1][ni], 0, 0, 0);
        }
    }
#pragma unroll
    for (int ni = 0; ni < 4; ++ni) {
        int col = co0 + ni * 16 + r;
        if (col < 216) {
            float bb = omb[col];
#pragma unroll
            for (int mi = 0; mi < 2; ++mi)
#pragma unroll
                for (int reg = 0; reg < 4; ++reg)
                    som[mi * 16 + kq * 4 + reg][col] = acc[mi][ni][reg] + bb;
        }
    }
    __syncthreads();
    int tid = threadIdx.x;
#pragma unroll
    for (int i = 0; i < 18; ++i) {
        int j = i * 256 + tid;          // 32*144 = 4608
        int px = j / 144, col = j - px * 144;
        offo[(size_t)(p0 + px) * 144 + col] = som[px][col];
    }
    int px = tid >> 3, g = tid & 7;
    float mx = -1e30f;
#pragma unroll
    for (int p = 0; p < 9; ++p) mx = fmaxf(mx, som[px][144 + g * 9 + p]);
    float e[9], s = 0.f;
#pragma unroll
    for (int p = 0; p < 9; ++p) { e[p] = expf(som[px][144 + g * 9 + p] - mx); s += e[p]; }
    float inv = 1.f / s;
#pragma unroll
    for (int p = 0; p < 9; ++p) msko[(size_t)(p0 + px) * 72 + g * 9 + p] = e[p] * inv;
}

// ---------------- DCNv3 deformable sampling core -> core_bf ----------------
__global__ __launch_bounds__(256) void k_core(const float* __restrict__ xp,
                                              const float* __restrict__ offo, const float* __restrict__ msko,
                                              unsigned short* __restrict__ core_bf) {
    int pix = blockIdx.x;
    int n = pix / HW_, hw = pix - n * HW_;
    int h = hw / W_,  w = hw - h * W_;
    int g  = threadIdx.x >> 5;
    int cc = threadIdx.x & 31;
    const float* op = offo + (size_t)pix * 144 + g * 18;
    const float* mp = msko + (size_t)pix * 72 + g * 9;
    const float* xg = xp + (size_t)n * HW_ * C_ + g * GC_ + cc;
    float acc = 0.f;
#pragma unroll
    for (int p = 0; p < 9; ++p) {
        float gx = (float)(w + (p / 3)) + op[p * 2];
        float gy = (float)(h + (p % 3)) + op[p * 2 + 1];
        float fx = floorf(gx), fy = floorf(gy);
        float wx = gx - fx,   wy = gy - fy;
        int ix = (int)fx - 1, iy = (int)fy - 1;
        float v00 = 0.f, v10 = 0.f, v01 = 0.f, v11 = 0.f;
        bool x0ok = (unsigned)ix < W_, x1ok = (unsigned)(ix + 1) < W_;
        bool y0ok = (unsigned)iy < H_, y1ok = (unsigned)(iy + 1) < H_;
        if (y0ok) {
            const float* rr = xg + (size_t)(iy * W_) * C_;
            if (x0ok) v00 = rr[(size_t)ix * C_];
            if (x1ok) v10 = rr[(size_t)(ix + 1) * C_];
        }
        if (y1ok) {
            const float* rr = xg + (size_t)((iy + 1) * W_) * C_;
            if (x0ok) v01 = rr[(size_t)ix * C_];
            if (x1ok) v11 = rr[(size_t)(ix + 1) * C_];
        }
        float sval = (v00 * (1.f - wx) + v10 * wx) * (1.f - wy)
                   + (v01 * (1.f - wx) + v11 * wx) * wy;
        acc = fmaf(mp[p], sval, acc);
    }
    core_bf[(size_t)pix * C_ + threadIdx.x] = f2bf(acc);
}

// ---------------- output proj MFMA + LN(1e-5) + gamma1 residual -> t, t_bf ----------------
__global__ __launch_bounds__(256) void k_outproj_mfma(const unsigned short* __restrict__ core_bf,
                                                      const unsigned short* __restrict__ outpwT,
                                                      const float* __restrict__ bo,
                                                      const float* __restrict__ g1, const float* __restrict__ lg,
                                                      const float* __restrict__ lb,
                                                      float* __restrict__ t, unsigned short* __restrict__ t_bf) {
    __shared__ float sd[32][260];
    int wave = threadIdx.x >> 6, lane = threadIdx.x & 63;
    int r = lane & 15, kq = lane >> 4;
    int p0 = blockIdx.x * 32, co0 = wave * 64;
    f32x4 acc[2][4] = {};
#pragma unroll 1
    for (int ks = 0; ks < 8; ++ks) {
        bf16x8 a0 = *(const bf16x8*)(core_bf + (size_t)(p0 + r) * C_ + ks * 32 + kq * 8);
        bf16x8 a1 = *(const bf16x8*)(core_bf + (size_t)(p0 + 16 + r) * C_ + ks * 32 + kq * 8);
        const unsigned short* bp = outpwT + (size_t)(co0 + r) * C_ + ks * 32 + kq * 8;
#pragma unroll
        for (int ni = 0; ni < 4; ++ni) {
            bf16x8 b = *(const bf16x8*)(bp + (size_t)ni * 16 * C_);
            acc[0][ni] = __builtin_amdgcn_mfma_f32_16x16x32_bf16(a0, b, acc[0][ni], 0, 0, 0);
            acc[1][ni] = __builtin_amdgcn_mfma_f32_16x16x32_bf16(a1, b, acc[1][ni], 0, 0, 0);
        }
    }
#pragma unroll
    for (int ni = 0; ni < 4; ++ni) {
        int col = co0 + ni * 16 + r;
        float bb = bo[col];
#pragma unroll
        for (int mi = 0; mi < 2; ++mi)
#pragma unroll
            for (int reg = 0; reg < 4; ++reg)
                sd[mi * 16 + kq * 4 + reg][col] = acc[mi][ni][reg] + bb;
    }
    __syncthreads();
    int px = threadIdx.x >> 3, sub = threadIdx.x & 7;
    float s1 = 0.f, s2 = 0.f;
#pragma unroll
    for (int i = 0; i < 8; ++i) {
        float4 vv = *(const float4*)&sd[px][sub * 32 + i * 4];
        s1 += vv.x + vv.y + vv.z + vv.w;
        s2 += vv.x * vv.x + vv.y * vv.y + vv.z * vv.z + vv.w * vv.w;
    }
#pragma unroll
    for (int off = 1; off < 8; off <<= 1) { s1 += __shfl_xor(s1, off, 64); s2 += __shfl_xor(s2, off, 64); }
    float mu  = s1 * (1.f / C_);
    float var = fmaxf(s2 * (1.f / C_) - mu * mu, 0.f);
    float rs  = rsqrtf(var + 1e-5f);
#pragma unroll
    for (int i = 0; i < 32; ++i) {
        int col = sub * 32 + i;
        size_t idx = (size_t)(p0 + px) * C_ + col;
        float tn = t[idx] + g1[col] * ((sd[px][col] - mu) * rs * lg[col] + lb[col]);
        t[idx] = tn;
        t_bf[idx] = f2bf(tn);
    }
}

// ---------------- fc1 GEMM (M=NHW,N=1024,K=256) + GELU -> h_bf ----------------
// 128x128 tile, 4 waves (2x2), BK=64; async global_load_lds into fragment-major chunks;
// output staged via padded LDS for coalesced 16B stores.
__global__ __launch_bounds__(256) void k_fc1_mfma(const unsigned short* __restrict__ t_bf,
                                                  const unsigned short* __restrict__ fc1wT,
                                                  const float* __restrict__ fc1b,
                                                  unsigned short* __restrict__ h_bf) {
    __shared__ __align__(16) unsigned char smem[34816];   // staging 32KB; out 128*136*2=34816B
    unsigned short* sm16 = (unsigned short*)smem;
    bf16x8* sA = (bf16x8*)smem;                 // 16 chunks * 64
    bf16x8* sB = (bf16x8*)(smem + 16384);       // 16 chunks * 64
    int tid = threadIdx.x;
    int wave = tid >> 6, lane = tid & 63;
    int r = lane & 15, kq = lane >> 4;
    int mt = blockIdx.x >> 3, nt = blockIdx.x & 7;
    int m0 = mt * 128, n0 = nt * 128;
    int wm = wave & 1, wn = wave >> 1;

    f32x4 acc[4][4] = {};
#pragma unroll 1
    for (int kt = 0; kt < 4; ++kt) {
        int k0 = kt * 64;
        if (kt) __syncthreads();               // previous tile's reads done
#pragma unroll
        for (int i = 0; i < 4; ++i) {          // A chunks q = wave*4+i
            int q = wave * 4 + i;
            int row = m0 + (q >> 1) * 16 + r;
            int cc  = (q & 1) * 4 + kq;
            GLOAD_LDS16(t_bf + (size_t)row * C_ + k0 + cc * 8, sm16 + q * 512);
        }
#pragma unroll
        for (int i = 0; i < 4; ++i) {          // B chunks q = wave*4+i
            int q = wave * 4 + i;
            int nrow = n0 + (q >> 1) * 16 + r;
            int cc   = (q & 1) * 4 + kq;
            GLOAD_LDS16(fc1wT + (size_t)nrow * C_ + k0 + cc * 8, sm16 + 8192 + q * 512);
        }
        __syncthreads();                       // drains vmcnt before barrier
#pragma unroll
        for (int ks = 0; ks < 2; ++ks) {
            bf16x8 af[4], bfr[4];
#pragma unroll
            for (int mi = 0; mi < 4; ++mi) af[mi]  = sA[((wm * 4 + mi) * 2 + ks) * 64 + lane];
#pragma unroll
            for (int ni = 0; ni < 4; ++ni) bfr[ni] = sB[((wn * 4 + ni) * 2 + ks) * 64 + lane];
#pragma unroll
            for (int mi = 0; mi < 4; ++mi)
#pragma unroll
                for (int ni = 0; ni < 4; ++ni)
                    acc[mi][ni] = __builtin_amdgcn_mfma_f32_16x16x32_bf16(af[mi], bfr[ni], acc[mi][ni], 0, 0, 0);
        }
    }
    __syncthreads();                           // all ds_reads done before out-staging overwrites
#pragma unroll
    for (int ni = 0; ni < 4; ++ni) {
        int col = (wn * 4 + ni) * 16 + r;
        float bb = fc1b[n0 + col];
#pragma unroll
        for (int mi = 0; mi < 4; ++mi)
#pragma unroll
            for (int reg = 0; reg < 4; ++reg) {
                int row = (wm * 4 + mi) * 16 + kq * 4 + reg;
                sm16[row * 136 + col] = f2bf(gelu_exact(acc[mi][ni][reg] + bb));
            }
    }
    __syncthreads();
    int trow = tid >> 1, thalf = tid & 1;
    const unsigned short* src = sm16 + trow * 136 + thalf * 64;
    unsigned short* dst = h_bf + (size_t)(m0 + trow) * HID_ + n0 + thalf * 64;
#pragma unroll
    for (int j = 0; j < 8; ++j)
        *(bf16x8*)(dst + j * 8) = *(const bf16x8*)(src + j * 8);
}

// ---------------- fc2 GEMM (M=NHW,N=256,K=1024) + LN(1e-5) + gamma2 residual, dbuf pipeline ----------------
__global__ __launch_bounds__(256) void k_fc2ln_mfma(const unsigned short* __restrict__ h_bf,
                                                    const unsigned short* __restrict__ fc2wT,
                                                    const float* __restrict__ fc2b,
                                                    const float* __restrict__ g2, const float* __restrict__ lg,
                                                    const float* __restrict__ lb, float* __restrict__ t) {
    __shared__ __align__(16) unsigned char smem[81920];   // 2 x (A 8KB + B 32KB)
    unsigned short* sm16 = (unsigned short*)smem;
    int tid = threadIdx.x;
    int wave = tid >> 6, lane = tid & 63;
    int r = lane & 15, kq = lane >> 4;
    int m0 = blockIdx.x * 64;

    f32x4 acc[16] = {};

    auto stage = [&](int kt, int buf) {
        int k0 = kt * 64;
        unsigned short* dstA = sm16 + buf * 20480;
        unsigned short* dstB = dstA + 4096;
#pragma unroll
        for (int i = 0; i < 2; ++i) {
            int q = wave * 2 + i;
            int row = m0 + wave * 16 + r;
            GLOAD_LDS16(h_bf + (size_t)row * HID_ + k0 + (i * 4 + kq) * 8, dstA + q * 512);
        }
#pragma unroll
        for (int i = 0; i < 8; ++i) {
            int q = wave * 8 + i;
            int nrow = (q >> 1) * 16 + r;
            int cc   = (q & 1) * 4 + kq;
            GLOAD_LDS16(fc2wT + (size_t)nrow * HID_ + k0 + cc * 8, dstB + q * 512);
        }
    };

    stage(0, 0);
    int cur = 0;
#pragma unroll 1
    for (int kt = 0; kt < 16; ++kt) {
        if (kt < 15) {
            stage(kt + 1, cur ^ 1);
            asm volatile("s_waitcnt vmcnt(10)" ::: "memory");
        } else {
            asm volatile("s_waitcnt vmcnt(0)" ::: "memory");
        }
        __builtin_amdgcn_s_barrier();
        bf16x8* sA = (bf16x8*)(sm16 + cur * 20480);
        bf16x8* sB = sA + 512;
#pragma unroll
        for (int ks = 0; ks < 2; ++ks) {
            bf16x8 a = sA[(wave * 2 + ks) * 64 + lane];
#pragma unroll
            for (int ni = 0; ni < 16; ++ni) {
                bf16x8 b = sB[(ni * 2 + ks) * 64 + lane];
                acc[ni] = __builtin_amdgcn_mfma_f32_16x16x32_bf16(a, b, acc[ni], 0, 0, 0);
            }
        }
        __builtin_amdgcn_s_barrier();
        cur ^= 1;
    }
    // epilogue: bias, per-row LN over 256 cols (in-wave), gamma2 residual into t
    float bb[16], g2v[16], lgv[16], lbv[16];
#pragma unroll
    for (int ni = 0; ni < 16; ++ni) {
        int col = ni * 16 + r;
        bb[ni] = fc2b[col]; g2v[ni] = g2[col]; lgv[ni] = lg[col]; lbv[ni] = lb[col];
    }
#pragma unroll
    for (int ni = 0; ni < 16; ++ni)
#pragma unroll
        for (int reg = 0; reg < 4; ++reg) acc[ni][reg] += bb[ni];
#pragma unroll
    for (int reg = 0; reg < 4; ++reg) {
        float s1 = 0.f, s2 = 0.f;
#pragma unroll
        for (int ni = 0; ni < 16; ++ni) { float vv = acc[ni][reg]; s1 += vv; s2 += vv * vv; }
#pragma unroll
        for (int off = 1; off < 16; off <<= 1) { s1 += __shfl_xor(s1, off, 64); s2 += __shfl_xor(s2, off, 64); }
        float mu  = s1 * (1.f / C_);
        float var = fmaxf(s2 * (1.f / C_) - mu * mu, 0.f);
        float rs  = rsqrtf(var + 1e-5f);
        int row = m0 + wave * 16 + kq * 4 + reg;
        float* tr = t + (size_t)row * C_;
#pragma unroll
        for (int ni = 0; ni < 16; ++ni) {
            int col = ni * 16 + r;
            tr[col] += g2v[ni] * ((acc[ni][reg] - mu) * rs * lgv[ni] + lbv[ni]);
        }
    }
}

// ---------------- BN2 + input residual + ReLU -> out (NCHW) ----------------
__global__ __launch_bounds__(256) void k_final(const float* __restrict__ t, const float* __restrict__ x,
                                               const float* __restrict__ g, const float* __restrict__ b,
                                               const float* __restrict__ m, const float* __restrict__ v,
                                               float* __restrict__ out) {
    int i  = blockIdx.x * 256 + threadIdx.x;
    int hw = i % HW_;
    int r  = i / HW_;
    int c  = r & 255;
    int n  = r >> 8;
    float tv  = t[(size_t)(n * HW_ + hw) * C_ + c];
    float s   = rsqrtf(v[c] + 1e-5f);
    float val = (tv - m[c]) * (g[c] * s) + b[c] + x[i];
    out[i] = fmaxf(val, 0.f);
}

extern "C" void kernel_launch(void* const* d_in, const int* in_sizes, int n_in,
                              void* d_out, int out_size, void* d_ws, size_t ws_size,
                              hipStream_t stream) {
    const float* x      = (const float*)d_in[0];
    const float* conv1w = (const float*)d_in[1];
    const float* bn1g   = (const float*)d_in[2];
    const float* bn1b   = (const float*)d_in[3];
    const float* bn1m   = (const float*)d_in[4];
    const float* bn1v   = (const float*)d_in[5];
    const float* ln1g   = (const float*)d_in[6];
    const float* ln1b   = (const float*)d_in[7];
    const float* dww    = (const float*)d_in[8];
    const float* dwb    = (const float*)d_in[9];
    const float* dwlng  = (const float*)d_in[10];
    const float* dwlnb  = (const float*)d_in[11];
    const float* offw   = (const float*)d_in[12];
    const float* offb   = (const float*)d_in[13];
    const float* mskw   = (const float*)d_in[14];
    const float* mskb   = (const float*)d_in[15];
    const float* inpw   = (const float*)d_in[16];
    const float* inpb   = (const float*)d_in[17];
    const float* outpw  = (const float*)d_in[18];
    const float* outpb  = (const float*)d_in[19];
    const float* gamma1 = (const float*)d_in[20];
    const float* ln2g   = (const float*)d_in[21];
    const float* ln2b   = (const float*)d_in[22];
    const float* fc1w   = (const float*)d_in[23];
    const float* fc1b   = (const float*)d_in[24];
    const float* fc2w   = (const float*)d_in[25];
    const float* fc2b   = (const float*)d_in[26];
    const float* gamma2 = (const float*)d_in[27];
    const float* bn2g   = (const float*)d_in[28];
    const float* bn2b   = (const float*)d_in[29];
    const float* bn2m   = (const float*)d_in[30];
    const float* bn2v   = (const float*)d_in[31];
    float* out = (float*)d_out;

    // ---- workspace layout (dead-by-MLP region first, aliased by h_bf) ----
    float* ws    = (float*)d_ws;
    float* xproj = ws;                                    // [NHW][256] f32   (dead after core)
    float* offo  = xproj + (size_t)NHW_ * C_;             // [NHW][144] f32   (dead after core)
    float* msko  = offo  + (size_t)NHW_ * 144;            // [NHW][72]  f32   (dead after core)
    unsigned short* x1_bf = (unsigned short*)(msko + (size_t)NHW_ * 72);   // [NHW][256] (dead after offmask)
    unsigned short* scr   = x1_bf + (size_t)NHW_ * C_;    // xpad / core_bf alias
    float* t     = (float*)(scr + (size_t)N_ * XP_H * XP_W * C_);          // [NHW][256] f32
    float* omb   = t + (size_t)NHW_ * C_;                 // [256] f32
    unsigned short* t_bf  = (unsigned short*)(omb + 256); // [NHW][256]
    unsigned short* wTT   = t_bf  + (size_t)NHW_ * C_;    // [9][256][256]
    unsigned short* inpwT = wTT   + (size_t)9 * C_ * C_;  // [256][256]
    unsigned short* outpwT= inpwT + (size_t)C_ * C_;
    unsigned short* fc1wT = outpwT+ (size_t)C_ * C_;      // [1024][256]
    unsigned short* fc2wT = fc1wT + (size_t)HID_ * C_;    // [256][1024]
    unsigned short* omT   = fc2wT + (size_t)C_ * HID_;    // [256][256]
    unsigned short* xpad    = scr;
    unsigned short* core_bf = scr;
    unsigned short* h_bf    = (unsigned short*)xproj;     // [NHW][1024] aliases xproj..x1_bf (51.4MB < 60.2MB)

    hipMemsetAsync(xpad, 0, (size_t)N_ * XP_H * XP_W * C_ * sizeof(unsigned short), stream);
    k_prep_xpad<<<N_ * H_, 256, 0, stream>>>(x, xpad);
    k_prep_wTT <<<2304,    256, 0, stream>>>(conv1w, wTT);
    k_prep_sqT <<<256,     256, 0, stream>>>(inpw, inpwT);
    k_prep_sqT <<<256,     256, 0, stream>>>(outpw, outpwT);
    k_prep_fc1T<<<1024,    256, 0, stream>>>(fc1w, fc1wT);
    k_prep_fc2T<<<256,     256, 0, stream>>>(fc2w, fc2wT);
    k_prep_om  <<<256,     256, 0, stream>>>(offw, offb, mskw, mskb, omT, omb);

    k_conv1_mfma  <<<(NHW_ / 64) * 2, 256, 0, stream>>>(xpad, wTT, bn1g, bn1b, bn1m, bn1v, t, t_bf);
    k_inproj_mfma <<<NHW_ / 64, 256, 0, stream>>>(t_bf, inpwT, inpb, xproj);
    k_dw          <<<NHW_,      256, 0, stream>>>(t, dww, dwb, dwlng, dwlnb, x1_bf);
    k_offmask_mfma<<<NHW_ / 32, 256, 0, stream>>>(x1_bf, omT, omb, offo, msko);
    k_core        <<<NHW_,      256, 0, stream>>>(xproj, offo, msko, core_bf);
    k_outproj_mfma<<<NHW_ / 32, 256, 0, stream>>>(core_bf, outpwT, outpb, gamma1, ln1g, ln1b, t, t_bf);
    k_fc1_mfma    <<<(NHW_ / 128) * 8, 256, 0, stream>>>(t_bf, fc1wT, fc1b, h_bf);
    k_fc2ln_mfma  <<<NHW_ / 64, 256, 0, stream>>>(h_bf, fc2wT, fc2b, gamma2, ln2g, ln2b, t);
    k_final       <<<NHW_,      256, 0, stream>>>(t, x, bn2g, bn2b, bn2m, bn2v, out);
}

// Round 9
// 625.028 us; speedup vs baseline: 1.4339x; 1.0351x over previous
//
#include <hip/hip_runtime.h>
#include <cmath>

#define N_   8
#define H_   56
#define W_   56
#define C_   256
#define HW_  3136
#define NHW_ 25088
#define G_   8
#define GC_  32
#define P_   9
#define HID_ 1024
#define XP_H 58
#define XP_W 58

typedef __attribute__((ext_vector_type(8))) short bf16x8;
typedef __attribute__((ext_vector_type(4))) float f32x4;

#define GLOAD_LDS16(g, l) __builtin_amdgcn_global_load_lds( \
    (const __attribute__((address_space(1))) void*)(g), \
    (__attribute__((address_space(3))) void*)(l), 16, 0, 0)

__device__ __forceinline__ unsigned short f2bf(float f) {
    unsigned u = __float_as_uint(f);
    u += 0x7FFF + ((u >> 16) & 1);   // round-to-nearest-even
    return (unsigned short)(u >> 16);
}

__device__ __forceinline__ float gelu_exact(float v) {
    return 0.5f * v * (1.f + erff(v * 0.70710678118654752f));
}

// ---------------- block-wide sum of (a,b) over 256 threads ----------------
__device__ __forceinline__ float2 block_sum2(float a, float b, float* sm) {
    int lane = threadIdx.x & 63;
    int wid  = threadIdx.x >> 6;
#pragma unroll
    for (int off = 32; off > 0; off >>= 1) {
        a += __shfl_down(a, off, 64);
        b += __shfl_down(b, off, 64);
    }
    if (lane == 0) { sm[wid] = a; sm[wid + 4] = b; }
    __syncthreads();
    float ra = sm[0] + sm[1] + sm[2] + sm[3];
    float rb = sm[4] + sm[5] + sm[6] + sm[7];
    __syncthreads();
    return make_float2(ra, rb);
}

// ---------------- x (NCHW fp32) -> xpad (N,58,58,256 bf16), border pre-zeroed ----------------
__global__ __launch_bounds__(256) void k_prep_xpad(const float* __restrict__ x, unsigned short* __restrict__ xpad) {
    int nh = blockIdx.x;                   // N_*H_ = 448
    int n = nh / H_, h = nh - n * H_;
    int c = threadIdx.x;
    const float* xr = x + ((size_t)(n * C_ + c)) * HW_ + h * W_;
    unsigned short* orow = xpad + ((size_t)((n * XP_H + h + 1) * XP_W + 1)) * C_ + c;
    for (int w = 0; w < W_; ++w) orow[(size_t)w * C_] = f2bf(xr[w]);
}

// ---------------- conv1 weights [co][ci][3][3] -> wTT [kk][co][ci] bf16 ----------------
__global__ __launch_bounds__(256) void k_prep_wTT(const float* __restrict__ w, unsigned short* __restrict__ wTT) {
    int i  = blockIdx.x * 256 + threadIdx.x;   // 9*256*256
    int ci = i & 255;
    int r  = i >> 8;
    int co = r & 255;
    int kk = r >> 8;
    wTT[i] = f2bf(w[(co * 256 + ci) * 9 + kk]);
}

// ---------------- square 256x256 weight -> W^T bf16 [n][k] ----------------
__global__ __launch_bounds__(256) void k_prep_sqT(const float* __restrict__ src, unsigned short* __restrict__ dst) {
    int n = blockIdx.x, k = threadIdx.x;
    dst[n * C_ + k] = f2bf(src[k * C_ + n]);
}

// ---------------- fc1 [256][1024] -> [1024][256] bf16 ----------------
__global__ __launch_bounds__(256) void k_prep_fc1T(const float* __restrict__ src, unsigned short* __restrict__ dst) {
    int n = blockIdx.x, k = threadIdx.x;
    dst[(size_t)n * C_ + k] = f2bf(src[(size_t)k * HID_ + n]);
}

// ---------------- fc2 [1024][256] -> [256][1024] bf16 ----------------
__global__ __launch_bounds__(256) void k_prep_fc2T(const float* __restrict__ src, unsigned short* __restrict__ dst) {
    int n = blockIdx.x, k0 = threadIdx.x;
#pragma unroll
    for (int q = 0; q < 4; ++q) {
        int k = q * 256 + k0;
        dst[(size_t)n * HID_ + k] = f2bf(src[(size_t)k * C_ + n]);
    }
}

// ---------------- offw[256][144] + mskw[256][72] -> omT [256][256] bf16 (+ omb) ----------------
__global__ __launch_bounds__(256) void k_prep_om(const float* __restrict__ offw, const float* __restrict__ offb,
                                                 const float* __restrict__ mskw, const float* __restrict__ mskb,
                                                 unsigned short* __restrict__ omT, float* __restrict__ omb) {
    int n = blockIdx.x, k = threadIdx.x;
    float v = 0.f;
    if (n < 144)      v = offw[k * 144 + n];
    else if (n < 216) v = mskw[k * 72 + (n - 144)];
    omT[n * C_ + k] = f2bf(v);
    if (k == 0) omb[n] = (n < 144) ? offb[n] : (n < 216 ? mskb[n - 144] : 0.f);
}

// ---------------- conv1 implicit GEMM: 64x128 tile, BK=64, dbuf + XCD-band swizzle ----------------
// swz gives each XCD a contiguous band of m-tiles -> its xpad slice (~1.7MB) fits per-XCD L2.
__global__ __launch_bounds__(256) void k_conv1_mfma(const unsigned short* __restrict__ xpad,
                                                    const unsigned short* __restrict__ wTT,
                                                    const float* __restrict__ g, const float* __restrict__ b,
                                                    const float* __restrict__ m, const float* __restrict__ v,
                                                    float* __restrict__ t, unsigned short* __restrict__ t_bf) {
    __shared__ __align__(16) unsigned char smem[49152];   // 2 x (A 8KB + B 16KB)
    unsigned short* sm16 = (unsigned short*)smem;
    int tid = threadIdx.x;
    int wave = tid >> 6, lane = tid & 63;
    int r = lane & 15, kq = lane >> 4;
    int bid = blockIdx.x;                    // 784 = 8 * 98
    int swz = (bid & 7) * 98 + (bid >> 3);   // bijective XCD-band swizzle
    int mt = swz >> 1, nt = swz & 1;
    int m0 = mt * 64, n0 = nt * 128;
    int wm = wave & 1, wn = wave >> 1;

    // per-lane A-row base: row = m0 + wave*16 + r
    int pix = m0 + wave * 16 + r;
    int n = pix / HW_, hw = pix - n * HW_;
    int h = hw / W_, w = hw - h * W_;
    size_t abase = ((size_t)((n * XP_H + h) * XP_W + w)) * C_;

    f32x4 acc[2][4] = {};

    auto stage = [&](int kt, int buf) {
        int tap = kt >> 2, ktk = kt & 3;
        int kh = tap / 3, kw = tap - kh * 3;
        int k0 = ktk * 64;
        unsigned short* dstA = sm16 + buf * 12288;
        unsigned short* dstB = dstA + 4096;
        const unsigned short* ap = xpad + abase + (size_t)(kh * XP_W + kw) * C_ + k0;
#pragma unroll
        for (int i = 0; i < 2; ++i)
            GLOAD_LDS16(ap + (i * 4 + kq) * 8, dstA + (wave * 2 + i) * 512);
#pragma unroll
        for (int i = 0; i < 4; ++i) {
            int q = wave * 4 + i;
            int nrow = n0 + (q >> 1) * 16 + r;
            int cc   = (q & 1) * 4 + kq;
            GLOAD_LDS16(wTT + ((size_t)(tap * C_) + nrow) * C_ + k0 + cc * 8, dstB + q * 512);
        }
    };

    stage(0, 0);
    int cur = 0;
#pragma unroll 1
    for (int kt = 0; kt < 36; ++kt) {
        if (kt < 35) {
            stage(kt + 1, cur ^ 1);
            asm volatile("s_waitcnt vmcnt(6)" ::: "memory");
        } else {
            asm volatile("s_waitcnt vmcnt(0)" ::: "memory");
        }
        __builtin_amdgcn_s_barrier();
        bf16x8* sA = (bf16x8*)(sm16 + cur * 12288);
        bf16x8* sB = sA + 512;
#pragma unroll
        for (int ks = 0; ks < 2; ++ks) {
            bf16x8 af[2], bfr[4];
#pragma unroll
            for (int mi = 0; mi < 2; ++mi) af[mi]  = sA[((wm * 2 + mi) * 2 + ks) * 64 + lane];
#pragma unroll
            for (int ni = 0; ni < 4; ++ni) bfr[ni] = sB[((wn * 4 + ni) * 2 + ks) * 64 + lane];
#pragma unroll
            for (int mi = 0; mi < 2; ++mi)
#pragma unroll
                for (int ni = 0; ni < 4; ++ni)
                    acc[mi][ni] = __builtin_amdgcn_mfma_f32_16x16x32_bf16(af[mi], bfr[ni], acc[mi][ni], 0, 0, 0);
        }
        __builtin_amdgcn_s_barrier();
        cur ^= 1;
    }

#pragma unroll
    for (int ni = 0; ni < 4; ++ni) {
        int co = n0 + (wn * 4 + ni) * 16 + r;
        float sc = g[co] * rsqrtf(v[co] + 1e-5f);
        float sh = b[co] - m[co] * sc;
#pragma unroll
        for (int mi = 0; mi < 2; ++mi) {
#pragma unroll
            for (int reg = 0; reg < 4; ++reg) {
                int po = m0 + (wm * 2 + mi) * 16 + kq * 4 + reg;
                float val = fmaxf(acc[mi][ni][reg] * sc + sh, 0.f);
                size_t idx = (size_t)po * C_ + co;
                t[idx] = val;
                t_bf[idx] = f2bf(val);
            }
        }
    }
}

// ---------------- input proj: 64x256 staged-dbuf GEMM (K=256) -> xproj f32 ----------------
__global__ __launch_bounds__(256) void k_inproj_mfma(const unsigned short* __restrict__ t_bf,
                                                     const unsigned short* __restrict__ inpwT,
                                                     const float* __restrict__ bias,
                                                     float* __restrict__ xproj) {
    __shared__ __align__(16) unsigned char smem[81920];   // 2 x (A 8KB + B 32KB)
    unsigned short* sm16 = (unsigned short*)smem;
    int tid = threadIdx.x;
    int wave = tid >> 6, lane = tid & 63;
    int r = lane & 15, kq = lane >> 4;
    int m0 = blockIdx.x * 64;

    f32x4 acc[16] = {};

    auto stage = [&](int kt, int buf) {
        int k0 = kt * 64;
        unsigned short* dstA = sm16 + buf * 20480;
        unsigned short* dstB = dstA + 4096;
#pragma unroll
        for (int i = 0; i < 2; ++i) {
            int q = wave * 2 + i;
            int row = m0 + wave * 16 + r;
            GLOAD_LDS16(t_bf + (size_t)row * C_ + k0 + (i * 4 + kq) * 8, dstA + q * 512);
        }
#pragma unroll
        for (int i = 0; i < 8; ++i) {
            int q = wave * 8 + i;
            int nrow = (q >> 1) * 16 + r;
            int cc   = (q & 1) * 4 + kq;
            GLOAD_LDS16(inpwT + (size_t)nrow * C_ + k0 + cc * 8, dstB + q * 512);
        }
    };

    stage(0, 0);
    int cur = 0;
#pragma unroll 1
    for (int kt = 0; kt < 4; ++kt) {
        if (kt < 3) {
            stage(kt + 1, cur ^ 1);
            asm volatile("s_waitcnt vmcnt(10)" ::: "memory");
        } else {
            asm volatile("s_waitcnt vmcnt(0)" ::: "memory");
        }
        __builtin_amdgcn_s_barrier();
        bf16x8* sA = (bf16x8*)(sm16 + cur * 20480);
        bf16x8* sB = sA + 512;
#pragma unroll
        for (int ks = 0; ks < 2; ++ks) {
            bf16x8 a = sA[(wave * 2 + ks) * 64 + lane];
#pragma unroll
            for (int ni = 0; ni < 16; ++ni) {
                bf16x8 b = sB[(ni * 2 + ks) * 64 + lane];
                acc[ni] = __builtin_amdgcn_mfma_f32_16x16x32_bf16(a, b, acc[ni], 0, 0, 0);
            }
        }
        __builtin_amdgcn_s_barrier();
        cur ^= 1;
    }

#pragma unroll
    for (int ni = 0; ni < 16; ++ni) {
        int col = ni * 16 + r;
        float bb = bias[col];
#pragma unroll
        for (int reg = 0; reg < 4; ++reg) {
            int row = m0 + wave * 16 + kq * 4 + reg;
            xproj[(size_t)row * C_ + col] = acc[ni][reg] + bb;
        }
    }
}

// ---------------- depthwise 3x3 + LN(1e-6) + exact GELU -> x1_bf ----------------
__global__ __launch_bounds__(256) void k_dw(const float* __restrict__ t, const float* __restrict__ dww,
                                            const float* __restrict__ dwb, const float* __restrict__ lg,
                                            const float* __restrict__ lb, unsigned short* __restrict__ x1_bf) {
    __shared__ float sm[8];
    int pix = blockIdx.x;
    int n = pix / HW_, hw = pix - n * HW_;
    int h = hw / W_,  w = hw - h * W_;
    int c = threadIdx.x;
    float acc = dwb[c];
#pragma unroll
    for (int kh = 0; kh < 3; ++kh) {
        int y = h + kh - 1;
        if ((unsigned)y >= H_) continue;
#pragma unroll
        for (int kw = 0; kw < 3; ++kw) {
            int xx = w + kw - 1;
            if ((unsigned)xx >= W_) continue;
            acc = fmaf(t[(size_t)(n * HW_ + y * W_ + xx) * C_ + c], dww[(kh * 3 + kw) * C_ + c], acc);
        }
    }
    float2 r  = block_sum2(acc, acc * acc, sm);
    float mu  = r.x * (1.f / C_);
    float var = fmaxf(r.y * (1.f / C_) - mu * mu, 0.f);
    float rs  = rsqrtf(var + 1e-6f);
    float val = (acc - mu) * rs * lg[c] + lb[c];
    x1_bf[(size_t)pix * C_ + c] = f2bf(gelu_exact(val));
}

// ---------------- offset+mask via MFMA (N=256: 144 off | 72 msk | 40 pad) + softmax ----------------
__global__ __launch_bounds__(256) void k_offmask_mfma(const unsigned short* __restrict__ x1_bf,
                                                      const unsigned short* __restrict__ omT,
                                                      const float* __restrict__ omb,
                                                      float* __restrict__ offo, float* __restrict__ msko) {
    __shared__ float som[32][225];
    int wave = threadIdx.x >> 6, lane = threadIdx.x & 63;
    int r = lane & 15, kq = lane >> 4;
    int p0 = blockIdx.x * 32, co0 = wave * 64;
    f32x4 acc[2][4] = {};
#pragma unroll 1
    for (int ks = 0; ks < 8; ++ks) {
        bf16x8 a0 = *(const bf16x8*)(x1_bf + (size_t)(p0 + r) * C_ + ks * 32 + kq * 8);
        bf16x8 a1 = *(const bf16x8*)(x1_bf + (size_t)(p0 + 16 + r) * C_ + ks * 32 + kq * 8);
        const unsigned short* bp = omT + (size_t)(co0 + r) * C_ + ks * 32 + kq * 8;
#pragma unroll
        for (int ni = 0; ni < 4; ++ni) {
            bf16x8 b = *(const bf16x8*)(bp + (size_t)ni * 16 * C_);
            acc[0][ni] = __builtin_amdgcn_mfma_f32_16x16x32_bf16(a0, b, acc[0][ni], 0, 0, 0);
            acc[1][ni] = __builtin_amdgcn_mfma_f32_16x16x32_bf16(a1, b, acc[1][ni], 0, 0, 0);
        }
    }
#pragma unroll
    for (int ni = 0; ni < 4; ++ni) {
        int col = co0 + ni * 16 + r;
        if (col < 216) {
            float bb = omb[col];
#pragma unroll
            for (int mi = 0; mi < 2; ++mi)
#pragma unroll
                for (int reg = 0; reg < 4; ++reg)
                    som[mi * 16 + kq * 4 + reg][col] = acc[mi][ni][reg] + bb;
        }
    }
    __syncthreads();
    int tid = threadIdx.x;
#pragma unroll
    for (int i = 0; i < 18; ++i) {
        int j = i * 256 + tid;          // 32*144 = 4608
        int px = j / 144, col = j - px * 144;
        offo[(size_t)(p0 + px) * 144 + col] = som[px][col];
    }
    int px = tid >> 3, g = tid & 7;
    float mx = -1e30f;
#pragma unroll
    for (int p = 0; p < 9; ++p) mx = fmaxf(mx, som[px][144 + g * 9 + p]);
    float e[9], s = 0.f;
#pragma unroll
    for (int p = 0; p < 9; ++p) { e[p] = expf(som[px][144 + g * 9 + p] - mx); s += e[p]; }
    float inv = 1.f / s;
#pragma unroll
    for (int p = 0; p < 9; ++p) msko[(size_t)(p0 + px) * 72 + g * 9 + p] = e[p] * inv;
}

// ---------------- DCNv3 deformable sampling core -> core_bf ----------------
__global__ __launch_bounds__(256) void k_core(const float* __restrict__ xp,
                                              const float* __restrict__ offo, const float* __restrict__ msko,
                                              unsigned short* __restrict__ core_bf) {
    int pix = blockIdx.x;
    int n = pix / HW_, hw = pix - n * HW_;
    int h = hw / W_,  w = hw - h * W_;
    int g  = threadIdx.x >> 5;
    int cc = threadIdx.x & 31;
    const float* op = offo + (size_t)pix * 144 + g * 18;
    const float* mp = msko + (size_t)pix * 72 + g * 9;
    const float* xg = xp + (size_t)n * HW_ * C_ + g * GC_ + cc;
    float acc = 0.f;
#pragma unroll
    for (int p = 0; p < 9; ++p) {
        float gx = (float)(w + (p / 3)) + op[p * 2];
        float gy = (float)(h + (p % 3)) + op[p * 2 + 1];
        float fx = floorf(gx), fy = floorf(gy);
        float wx = gx - fx,   wy = gy - fy;
        int ix = (int)fx - 1, iy = (int)fy - 1;
        float v00 = 0.f, v10 = 0.f, v01 = 0.f, v11 = 0.f;
        bool x0ok = (unsigned)ix < W_, x1ok = (unsigned)(ix + 1) < W_;
        bool y0ok = (unsigned)iy < H_, y1ok = (unsigned)(iy + 1) < H_;
        if (y0ok) {
            const float* rr = xg + (size_t)(iy * W_) * C_;
            if (x0ok) v00 = rr[(size_t)ix * C_];
            if (x1ok) v10 = rr[(size_t)(ix + 1) * C_];
        }
        if (y1ok) {
            const float* rr = xg + (size_t)((iy + 1) * W_) * C_;
            if (x0ok) v01 = rr[(size_t)ix * C_];
            if (x1ok) v11 = rr[(size_t)(ix + 1) * C_];
        }
        float sval = (v00 * (1.f - wx) + v10 * wx) * (1.f - wy)
                   + (v01 * (1.f - wx) + v11 * wx) * wy;
        acc = fmaf(mp[p], sval, acc);
    }
    core_bf[(size_t)pix * C_ + threadIdx.x] = f2bf(acc);
}

// ---------------- output proj MFMA + LN(1e-5) + gamma1 residual -> t, t_bf ----------------
__global__ __launch_bounds__(256) void k_outproj_mfma(const unsigned short* __restrict__ core_bf,
                                                      const unsigned short* __restrict__ outpwT,
                                                      const float* __restrict__ bo,
                                                      const float* __restrict__ g1, const float* __restrict__ lg,
                                                      const float* __restrict__ lb,
                                                      float* __restrict__ t, unsigned short* __restrict__ t_bf) {
    __shared__ float sd[32][260];
    int wave = threadIdx.x >> 6, lane = threadIdx.x & 63;
    int r = lane & 15, kq = lane >> 4;
    int p0 = blockIdx.x * 32, co0 = wave * 64;
    f32x4 acc[2][4] = {};
#pragma unroll 1
    for (int ks = 0; ks < 8; ++ks) {
        bf16x8 a0 = *(const bf16x8*)(core_bf + (size_t)(p0 + r) * C_ + ks * 32 + kq * 8);
        bf16x8 a1 = *(const bf16x8*)(core_bf + (size_t)(p0 + 16 + r) * C_ + ks * 32 + kq * 8);
        const unsigned short* bp = outpwT + (size_t)(co0 + r) * C_ + ks * 32 + kq * 8;
#pragma unroll
        for (int ni = 0; ni < 4; ++ni) {
            bf16x8 b = *(const bf16x8*)(bp + (size_t)ni * 16 * C_);
            acc[0][ni] = __builtin_amdgcn_mfma_f32_16x16x32_bf16(a0, b, acc[0][ni], 0, 0, 0);
            acc[1][ni] = __builtin_amdgcn_mfma_f32_16x16x32_bf16(a1, b, acc[1][ni], 0, 0, 0);
        }
    }
#pragma unroll
    for (int ni = 0; ni < 4; ++ni) {
        int col = co0 + ni * 16 + r;
        float bb = bo[col];
#pragma unroll
        for (int mi = 0; mi < 2; ++mi)
#pragma unroll
            for (int reg = 0; reg < 4; ++reg)
                sd[mi * 16 + kq * 4 + reg][col] = acc[mi][ni][reg] + bb;
    }
    __syncthreads();
    int px = threadIdx.x >> 3, sub = threadIdx.x & 7;
    float s1 = 0.f, s2 = 0.f;
#pragma unroll
    for (int i = 0; i < 8; ++i) {
        float4 vv = *(const float4*)&sd[px][sub * 32 + i * 4];
        s1 += vv.x + vv.y + vv.z + vv.w;
        s2 += vv.x * vv.x + vv.y * vv.y + vv.z * vv.z + vv.w * vv.w;
    }
#pragma unroll
    for (int off = 1; off < 8; off <<= 1) { s1 += __shfl_xor(s1, off, 64); s2 += __shfl_xor(s2, off, 64); }
    float mu  = s1 * (1.f / C_);
    float var = fmaxf(s2 * (1.f / C_) - mu * mu, 0.f);
    float rs  = rsqrtf(var + 1e-5f);
#pragma unroll
    for (int i = 0; i < 32; ++i) {
        int col = sub * 32 + i;
        size_t idx = (size_t)(p0 + px) * C_ + col;
        float tn = t[idx] + g1[col] * ((sd[px][col] - mu) * rs * lg[col] + lb[col]);
        t[idx] = tn;
        t_bf[idx] = f2bf(tn);
    }
}

// ---------------- fc1 GEMM (M=NHW,N=1024,K=256) + GELU -> h_bf ----------------
__global__ __launch_bounds__(256) void k_fc1_mfma(const unsigned short* __restrict__ t_bf,
                                                  const unsigned short* __restrict__ fc1wT,
                                                  const float* __restrict__ fc1b,
                                                  unsigned short* __restrict__ h_bf) {
    __shared__ __align__(16) unsigned char smem[34816];   // staging 32KB; out 128*136*2=34816B
    unsigned short* sm16 = (unsigned short*)smem;
    bf16x8* sA = (bf16x8*)smem;                 // 16 chunks * 64
    bf16x8* sB = (bf16x8*)(smem + 16384);       // 16 chunks * 64
    int tid = threadIdx.x;
    int wave = tid >> 6, lane = tid & 63;
    int r = lane & 15, kq = lane >> 4;
    int mt = blockIdx.x >> 3, nt = blockIdx.x & 7;
    int m0 = mt * 128, n0 = nt * 128;
    int wm = wave & 1, wn = wave >> 1;

    f32x4 acc[4][4] = {};
#pragma unroll 1
    for (int kt = 0; kt < 4; ++kt) {
        int k0 = kt * 64;
        if (kt) __syncthreads();
#pragma unroll
        for (int i = 0; i < 4; ++i) {          // A chunks q = wave*4+i
            int q = wave * 4 + i;
            int row = m0 + (q >> 1) * 16 + r;
            int cc  = (q & 1) * 4 + kq;
            GLOAD_LDS16(t_bf + (size_t)row * C_ + k0 + cc * 8, sm16 + q * 512);
        }
#pragma unroll
        for (int i = 0; i < 4; ++i) {          // B chunks q = wave*4+i
            int q = wave * 4 + i;
            int nrow = n0 + (q >> 1) * 16 + r;
            int cc   = (q & 1) * 4 + kq;
            GLOAD_LDS16(fc1wT + (size_t)nrow * C_ + k0 + cc * 8, sm16 + 8192 + q * 512);
        }
        __syncthreads();
#pragma unroll
        for (int ks = 0; ks < 2; ++ks) {
            bf16x8 af[4], bfr[4];
#pragma unroll
            for (int mi = 0; mi < 4; ++mi) af[mi]  = sA[((wm * 4 + mi) * 2 + ks) * 64 + lane];
#pragma unroll
            for (int ni = 0; ni < 4; ++ni) bfr[ni] = sB[((wn * 4 + ni) * 2 + ks) * 64 + lane];
#pragma unroll
            for (int mi = 0; mi < 4; ++mi)
#pragma unroll
                for (int ni = 0; ni < 4; ++ni)
                    acc[mi][ni] = __builtin_amdgcn_mfma_f32_16x16x32_bf16(af[mi], bfr[ni], acc[mi][ni], 0, 0, 0);
        }
    }
    __syncthreads();
#pragma unroll
    for (int ni = 0; ni < 4; ++ni) {
        int col = (wn * 4 + ni) * 16 + r;
        float bb = fc1b[n0 + col];
#pragma unroll
        for (int mi = 0; mi < 4; ++mi)
#pragma unroll
            for (int reg = 0; reg < 4; ++reg) {
                int row = (wm * 4 + mi) * 16 + kq * 4 + reg;
                sm16[row * 136 + col] = f2bf(gelu_exact(acc[mi][ni][reg] + bb));
            }
    }
    __syncthreads();
    int trow = tid >> 1, thalf = tid & 1;
    const unsigned short* src = sm16 + trow * 136 + thalf * 64;
    unsigned short* dst = h_bf + (size_t)(m0 + trow) * HID_ + n0 + thalf * 64;
#pragma unroll
    for (int j = 0; j < 8; ++j)
        *(bf16x8*)(dst + j * 8) = *(const bf16x8*)(src + j * 8);
}

// ---------------- fc2 GEMM + LN + gamma2 residual + BN2 + x-residual + ReLU -> out (NCHW) ----------------
// 64x256 tile, dbuf pipeline; epilogue stages final rows in LDS then writes NCHW coalesced.
__global__ __launch_bounds__(256) void k_fc2fin_mfma(const unsigned short* __restrict__ h_bf,
                                                     const unsigned short* __restrict__ fc2wT,
                                                     const float* __restrict__ fc2b,
                                                     const float* __restrict__ g2, const float* __restrict__ lg,
                                                     const float* __restrict__ lb, const float* __restrict__ t,
                                                     const float* __restrict__ x,
                                                     const float* __restrict__ bn2g, const float* __restrict__ bn2b,
                                                     const float* __restrict__ bn2m, const float* __restrict__ bn2v,
                                                     float* __restrict__ out) {
    __shared__ __align__(16) unsigned char smem[81920];   // 2 x (A 8KB + B 32KB); reused as ot[64][257] f32
    unsigned short* sm16 = (unsigned short*)smem;
    int tid = threadIdx.x;
    int wave = tid >> 6, lane = tid & 63;
    int r = lane & 15, kq = lane >> 4;
    int m0 = blockIdx.x * 64;

    f32x4 acc[16] = {};

    auto stage = [&](int kt, int buf) {
        int k0 = kt * 64;
        unsigned short* dstA = sm16 + buf * 20480;
        unsigned short* dstB = dstA + 4096;
#pragma unroll
        for (int i = 0; i < 2; ++i) {
            int q = wave * 2 + i;
            int row = m0 + wave * 16 + r;
            GLOAD_LDS16(h_bf + (size_t)row * HID_ + k0 + (i * 4 + kq) * 8, dstA + q * 512);
        }
#pragma unroll
        for (int i = 0; i < 8; ++i) {
            int q = wave * 8 + i;
            int nrow = (q >> 1) * 16 + r;
            int cc   = (q & 1) * 4 + kq;
            GLOAD_LDS16(fc2wT + (size_t)nrow * HID_ + k0 + cc * 8, dstB + q * 512);
        }
    };

    stage(0, 0);
    int cur = 0;
#pragma unroll 1
    for (int kt = 0; kt < 16; ++kt) {
        if (kt < 15) {
            stage(kt + 1, cur ^ 1);
            asm volatile("s_waitcnt vmcnt(10)" ::: "memory");
        } else {
            asm volatile("s_waitcnt vmcnt(0)" ::: "memory");
        }
        __builtin_amdgcn_s_barrier();
        bf16x8* sA = (bf16x8*)(sm16 + cur * 20480);
        bf16x8* sB = sA + 512;
#pragma unroll
        for (int ks = 0; ks < 2; ++ks) {
            bf16x8 a = sA[(wave * 2 + ks) * 64 + lane];
#pragma unroll
            for (int ni = 0; ni < 16; ++ni) {
                bf16x8 b = sB[(ni * 2 + ks) * 64 + lane];
                acc[ni] = __builtin_amdgcn_mfma_f32_16x16x32_bf16(a, b, acc[ni], 0, 0, 0);
            }
        }
        __builtin_amdgcn_s_barrier();
        cur ^= 1;
    }

    // epilogue 1: bias, per-row LN (in-wave), gamma2 residual -> ot[64][257] in LDS
    float* ot = (float*)smem;
    float bb[16], g2v[16], lgv[16], lbv[16];
#pragma unroll
    for (int ni = 0; ni < 16; ++ni) {
        int col = ni * 16 + r;
        bb[ni] = fc2b[col]; g2v[ni] = g2[col]; lgv[ni] = lg[col]; lbv[ni] = lb[col];
    }
#pragma unroll
    for (int ni = 0; ni < 16; ++ni)
#pragma unroll
        for (int reg = 0; reg < 4; ++reg) acc[ni][reg] += bb[ni];
#pragma unroll
    for (int reg = 0; reg < 4; ++reg) {
        float s1 = 0.f, s2 = 0.f;
#pragma unroll
        for (int ni = 0; ni < 16; ++ni) { float vv = acc[ni][reg]; s1 += vv; s2 += vv * vv; }
#pragma unroll
        for (int off = 1; off < 16; off <<= 1) { s1 += __shfl_xor(s1, off, 64); s2 += __shfl_xor(s2, off, 64); }
        float mu  = s1 * (1.f / C_);
        float var = fmaxf(s2 * (1.f / C_) - mu * mu, 0.f);
        float rs  = rsqrtf(var + 1e-5f);
        int row_local = wave * 16 + kq * 4 + reg;
        const float* tr = t + (size_t)(m0 + row_local) * C_;
#pragma unroll
        for (int ni = 0; ni < 16; ++ni) {
            int col = ni * 16 + r;
            ot[row_local * 257 + col] = tr[col] + g2v[ni] * ((acc[ni][reg] - mu) * rs * lgv[ni] + lbv[ni]);
        }
    }
    __syncthreads();

    // epilogue 2: BN2 + x residual + ReLU, NCHW coalesced writes (lane = hw, per-channel 256B runs)
    int n  = m0 / HW_;
    int hw0 = m0 - n * HW_;
#pragma unroll 1
    for (int i = 0; i < 64; ++i) {
        int c = wave * 64 + i;                 // wave-uniform channel
        float sc = bn2g[c] * rsqrtf(bn2v[c] + 1e-5f);
        float sh = bn2b[c] - bn2m[c] * sc;
        size_t gidx = ((size_t)(n * C_ + c)) * HW_ + hw0 + lane;
        float val = ot[lane * 257 + c] * sc + sh + x[gidx];
        out[gidx] = fmaxf(val, 0.f);
    }
}

extern "C" void kernel_launch(void* const* d_in, const int* in_sizes, int n_in,
                              void* d_out, int out_size, void* d_ws, size_t ws_size,
                              hipStream_t stream) {
    const float* x      = (const float*)d_in[0];
    const float* conv1w = (const float*)d_in[1];
    const float* bn1g   = (const float*)d_in[2];
    const float* bn1b   = (const float*)d_in[3];
    const float* bn1m   = (const float*)d_in[4];
    const float* bn1v   = (const float*)d_in[5];
    const float* ln1g   = (const float*)d_in[6];
    const float* ln1b   = (const float*)d_in[7];
    const float* dww    = (const float*)d_in[8];
    const float* dwb    = (const float*)d_in[9];
    const float* dwlng  = (const float*)d_in[10];
    const float* dwlnb  = (const float*)d_in[11];
    const float* offw   = (const float*)d_in[12];
    const float* offb   = (const float*)d_in[13];
    const float* mskw   = (const float*)d_in[14];
    const float* mskb   = (const float*)d_in[15];
    const float* inpw   = (const float*)d_in[16];
    const float* inpb   = (const float*)d_in[17];
    const float* outpw  = (const float*)d_in[18];
    const float* outpb  = (const float*)d_in[19];
    const float* gamma1 = (const float*)d_in[20];
    const float* ln2g   = (const float*)d_in[21];
    const float* ln2b   = (const float*)d_in[22];
    const float* fc1w   = (const float*)d_in[23];
    const float* fc1b   = (const float*)d_in[24];
    const float* fc2w   = (const float*)d_in[25];
    const float* fc2b   = (const float*)d_in[26];
    const float* gamma2 = (const float*)d_in[27];
    const float* bn2g   = (const float*)d_in[28];
    const float* bn2b   = (const float*)d_in[29];
    const float* bn2m   = (const float*)d_in[30];
    const float* bn2v   = (const float*)d_in[31];
    float* out = (float*)d_out;

    // ---- workspace layout (dead-by-MLP region first, aliased by h_bf) ----
    float* ws    = (float*)d_ws;
    float* xproj = ws;                                    // [NHW][256] f32   (dead after core)
    float* offo  = xproj + (size_t)NHW_ * C_;             // [NHW][144] f32   (dead after core)
    float* msko  = offo  + (size_t)NHW_ * 144;            // [NHW][72]  f32   (dead after core)
    unsigned short* x1_bf = (unsigned short*)(msko + (size_t)NHW_ * 72);   // [NHW][256] (dead after offmask)
    unsigned short* scr   = x1_bf + (size_t)NHW_ * C_;    // xpad / core_bf alias
    float* t     = (float*)(scr + (size_t)N_ * XP_H * XP_W * C_);          // [NHW][256] f32
    float* omb   = t + (size_t)NHW_ * C_;                 // [256] f32
    unsigned short* t_bf  = (unsigned short*)(omb + 256); // [NHW][256]
    unsigned short* wTT   = t_bf  + (size_t)NHW_ * C_;    // [9][256][256]
    unsigned short* inpwT = wTT   + (size_t)9 * C_ * C_;  // [256][256]
    unsigned short* outpwT= inpwT + (size_t)C_ * C_;
    unsigned short* fc1wT = outpwT+ (size_t)C_ * C_;      // [1024][256]
    unsigned short* fc2wT = fc1wT + (size_t)HID_ * C_;    // [256][1024]
    unsigned short* omT   = fc2wT + (size_t)C_ * HID_;    // [256][256]
    unsigned short* xpad    = scr;
    unsigned short* core_bf = scr;
    unsigned short* h_bf    = (unsigned short*)xproj;     // [NHW][1024] aliases xproj..x1_bf (51.4MB < 60.2MB)

    hipMemsetAsync(xpad, 0, (size_t)N_ * XP_H * XP_W * C_ * sizeof(unsigned short), stream);
    k_prep_xpad<<<N_ * H_, 256, 0, stream>>>(x, xpad);
    k_prep_wTT <<<2304,    256, 0, stream>>>(conv1w, wTT);
    k_prep_sqT <<<256,     256, 0, stream>>>(inpw, inpwT);
    k_prep_sqT <<<256,     256, 0, stream>>>(outpw, outpwT);
    k_prep_fc1T<<<1024,    256, 0, stream>>>(fc1w, fc1wT);
    k_prep_fc2T<<<256,     256, 0, stream>>>(fc2w, fc2wT);
    k_prep_om  <<<256,     256, 0, stream>>>(offw, offb, mskw, mskb, omT, omb);

    k_conv1_mfma  <<<(NHW_ / 64) * 2, 256, 0, stream>>>(xpad, wTT, bn1g, bn1b, bn1m, bn1v, t, t_bf);
    k_inproj_mfma <<<NHW_ / 64, 256, 0, stream>>>(t_bf, inpwT, inpb, xproj);
    k_dw          <<<NHW_,      256, 0, stream>>>(t, dww, dwb, dwlng, dwlnb, x1_bf);
    k_offmask_mfma<<<NHW_ / 32, 256, 0, stream>>>(x1_bf, omT, omb, offo, msko);
    k_core        <<<NHW_,      256, 0, stream>>>(xproj, offo, msko, core_bf);
    k_outproj_mfma<<<NHW_ / 32, 256, 0, stream>>>(core_bf, outpwT, outpb, gamma1, ln1g, ln1b, t, t_bf);
    k_fc1_mfma    <<<(NHW_ / 128) * 8, 256, 0, stream>>>(t_bf, fc1wT, fc1b, h_bf);
    k_fc2fin_mfma <<<NHW_ / 64, 256, 0, stream>>>(h_bf, fc2wT, fc2b, gamma2, ln2g, ln2b, t,
                                                  x, bn2g, bn2b, bn2m, bn2v, out);
}